// Round 5
// baseline (1099.644 us; speedup 1.0000x reference)
//
#include <hip/hip_runtime.h>
#include <math.h>

#define BQ    8192
#define DIMD  256
#define NSUB  16
#define KC    1024
#define ED    16
#define KLDS  832          // codebook rows staged in LDS (tail 192 via L1/L2)
#define PARTS 4

#define OFF_ZQ   1
#define OFF_OH   (1 + BQ * DIMD)            // 2097153
#define OH_ELEMS (BQ * NSUB * KC)           // 134217728
#define OFF_IDX  (OFF_OH + OH_ELEMS)        // 136314881
#define F4N      ((OH_ELEMS - 4) / 4)       // aligned float4 slots in onehot
#define WEPS     1e-4f                      // candidate window (v-units)

typedef __attribute__((ext_vector_type(2))) float v2f;

struct Zr  { v2f p0, p1, p2, p3, p4, p5, p6, p7; };   // one residual (16 f)
struct Row { float4 c0, c1, c2, c3; };                 // one codebook row
struct V2x2 { v2f lo, hi; };

// fast value: a = eh - sum(z_i * c_i), packed fp32 FMA (v_pk_fma_f32).
// Pure speed path; WEPS window absorbs its rounding (<~1e-6).
__device__ __forceinline__ float fastv(Zr z, Row rw, float eh) {
  V2x2 a0 = __builtin_bit_cast(V2x2, rw.c0);
  V2x2 a1 = __builtin_bit_cast(V2x2, rw.c1);
  V2x2 a2 = __builtin_bit_cast(V2x2, rw.c2);
  V2x2 a3 = __builtin_bit_cast(V2x2, rw.c3);
  v2f acc = {eh, 0.f};
  acc = __builtin_elementwise_fma(-z.p0, a0.lo, acc);
  acc = __builtin_elementwise_fma(-z.p1, a0.hi, acc);
  acc = __builtin_elementwise_fma(-z.p2, a1.lo, acc);
  acc = __builtin_elementwise_fma(-z.p3, a1.hi, acc);
  acc = __builtin_elementwise_fma(-z.p4, a2.lo, acc);
  acc = __builtin_elementwise_fma(-z.p5, a2.hi, acc);
  acc = __builtin_elementwise_fma(-z.p6, a3.lo, acc);
  acc = __builtin_elementwise_fma(-z.p7, a3.hi, acc);
  return acc.x + acc.y;
}

// numpy pairwise sum-of-squares (verified R3): r_j=q_j+q_{j+8}, tree combine.
__device__ __forceinline__ float np_sumsq(Zr z) {
  float q0 = __fmul_rn(z.p0.x, z.p0.x), q1 = __fmul_rn(z.p0.y, z.p0.y);
  float q2 = __fmul_rn(z.p1.x, z.p1.x), q3 = __fmul_rn(z.p1.y, z.p1.y);
  float q4 = __fmul_rn(z.p2.x, z.p2.x), q5 = __fmul_rn(z.p2.y, z.p2.y);
  float q6 = __fmul_rn(z.p3.x, z.p3.x), q7 = __fmul_rn(z.p3.y, z.p3.y);
  float q8 = __fmul_rn(z.p4.x, z.p4.x), q9 = __fmul_rn(z.p4.y, z.p4.y);
  float qa = __fmul_rn(z.p5.x, z.p5.x), qb = __fmul_rn(z.p5.y, z.p5.y);
  float qc = __fmul_rn(z.p6.x, z.p6.x), qd = __fmul_rn(z.p6.y, z.p6.y);
  float qe = __fmul_rn(z.p7.x, z.p7.x), qf = __fmul_rn(z.p7.y, z.p7.y);
  float r0 = __fadd_rn(q0, q8), r1 = __fadd_rn(q1, q9);
  float r2 = __fadd_rn(q2, qa), r3 = __fadd_rn(q3, qb);
  float r4 = __fadd_rn(q4, qc), r5 = __fadd_rn(q5, qd);
  float r6 = __fadd_rn(q6, qe), r7 = __fadd_rn(q7, qf);
  return __fadd_rn(__fadd_rn(__fadd_rn(r0, r1), __fadd_rn(r2, r3)),
                   __fadd_rn(__fadd_rn(r4, r5), __fadd_rn(r6, r7)));
}

// Reference-rounded distance (verified R3): SSE-lane einsum SOP + hadd,
// step-rounded d^2 assembly, fp64 sqrt (correctly rounded, CPU-bit-exact).
__device__ __forceinline__ float ref_d(Zr z, Row rw, float zsq, float esq) {
  float p0  = __fmul_rn(z.p0.x, rw.c0.x), p1  = __fmul_rn(z.p0.y, rw.c0.y);
  float p2  = __fmul_rn(z.p1.x, rw.c0.z), p3  = __fmul_rn(z.p1.y, rw.c0.w);
  float p4  = __fmul_rn(z.p2.x, rw.c1.x), p5  = __fmul_rn(z.p2.y, rw.c1.y);
  float p6  = __fmul_rn(z.p3.x, rw.c1.z), p7  = __fmul_rn(z.p3.y, rw.c1.w);
  float p8  = __fmul_rn(z.p4.x, rw.c2.x), p9  = __fmul_rn(z.p4.y, rw.c2.y);
  float p10 = __fmul_rn(z.p5.x, rw.c2.z), p11 = __fmul_rn(z.p5.y, rw.c2.w);
  float p12 = __fmul_rn(z.p6.x, rw.c3.x), p13 = __fmul_rn(z.p6.y, rw.c3.y);
  float p14 = __fmul_rn(z.p7.x, rw.c3.z), p15 = __fmul_rn(z.p7.y, rw.c3.w);
  float L0 = __fadd_rn(__fadd_rn(__fadd_rn(p0, p4), p8),  p12);
  float L1 = __fadd_rn(__fadd_rn(__fadd_rn(p1, p5), p9),  p13);
  float L2 = __fadd_rn(__fadd_rn(__fadd_rn(p2, p6), p10), p14);
  float L3 = __fadd_rn(__fadd_rn(__fadd_rn(p3, p7), p11), p15);
  float cross = __fadd_rn(__fadd_rn(L0, L1), __fadd_rn(L2, L3));
  float t = __fsub_rn(zsq, __fmul_rn(2.0f, cross));
  t = __fadd_rn(t, esq);
  t = fmaxf(t, 0.0f);
  return (float)sqrt((double)t);
}

__device__ __forceinline__ Zr sub_row(Zr z, Row rw) {   // elementwise __fsub_rn
  Zr o;
  o.p0 = (v2f){__fsub_rn(z.p0.x, rw.c0.x), __fsub_rn(z.p0.y, rw.c0.y)};
  o.p1 = (v2f){__fsub_rn(z.p1.x, rw.c0.z), __fsub_rn(z.p1.y, rw.c0.w)};
  o.p2 = (v2f){__fsub_rn(z.p2.x, rw.c1.x), __fsub_rn(z.p2.y, rw.c1.y)};
  o.p3 = (v2f){__fsub_rn(z.p3.x, rw.c1.z), __fsub_rn(z.p3.y, rw.c1.w)};
  o.p4 = (v2f){__fsub_rn(z.p4.x, rw.c2.x), __fsub_rn(z.p4.y, rw.c2.y)};
  o.p5 = (v2f){__fsub_rn(z.p5.x, rw.c2.z), __fsub_rn(z.p5.y, rw.c2.w)};
  o.p6 = (v2f){__fsub_rn(z.p6.x, rw.c3.x), __fsub_rn(z.p6.y, rw.c3.y)};
  o.p7 = (v2f){__fsub_rn(z.p7.x, rw.c3.z), __fsub_rn(z.p7.y, rw.c3.w)};
  return o;
}

__device__ __forceinline__ Zr load_zr(const float* p) {
  const float4* zp = (const float4*)p;
  float4 a0 = zp[0], a1 = zp[1], a2 = zp[2], a3 = zp[3];
  V2x2 v0 = __builtin_bit_cast(V2x2, a0), v1 = __builtin_bit_cast(V2x2, a1);
  V2x2 v2 = __builtin_bit_cast(V2x2, a2), v3 = __builtin_bit_cast(V2x2, a3);
  Zr z;
  z.p0 = v0.lo; z.p1 = v0.hi; z.p2 = v1.lo; z.p3 = v1.hi;
  z.p4 = v2.lo; z.p5 = v2.hi; z.p6 = v3.lo; z.p7 = v3.hi;
  return z;
}

// ---------------------------------------------------------------------------
// Kernel 1: block = 256 scans x 1 n; thread = 4 scans x 1/4 of k-range.
// Per depth: pass A (pure packed-FMA min), pass B (ref-rounded re-eval only
// within WEPS of final min), cross-part merge via packed (d_bits,k) u64.
// All state in named structs/scalars — no scratch arrays.
// ---------------------------------------------------------------------------
__global__ __launch_bounds__(256, 2) void vq_main(
    const float* __restrict__ z, const float* __restrict__ emb,
    float* __restrict__ out) {
  __shared__ float cb[KLDS * ED];                 // 53248 B
  __shared__ float esq[KC];                       // 4096 B
  __shared__ unsigned long long mrg[256 * PARTS]; // 8192 B  (total 65536)
  const int tid   = threadIdx.x;
  const int bx    = blockIdx.x;
  const int n     = bx & 15;
  const int bbase = (bx >> 4) * 256;
  const int part  = tid >> 6;          // wave id: k-range wave-uniform
  const int q     = tid & 63;
  const float* embn = emb + n * (KC * ED);

  {
    const float4* src = (const float4*)embn;
    float4* dst = (float4*)cb;
    for (int i = tid; i < KLDS * ED / 4; i += 256) dst[i] = src[i];
  }
  __syncthreads();
  for (int k = tid; k < KC; k += 256) {
    const float* cr = (k < KLDS) ? (cb + k * 16) : (embn + k * 16);
    Row rw;
    const float4* cp = (const float4*)cr;
    rw.c0 = cp[0]; rw.c1 = cp[1]; rw.c2 = cp[2]; rw.c3 = cp[3];
    // reuse load_zr layout for sumsq (same element order)
    V2x2 v0 = __builtin_bit_cast(V2x2, rw.c0), v1 = __builtin_bit_cast(V2x2, rw.c1);
    V2x2 v2 = __builtin_bit_cast(V2x2, rw.c2), v3 = __builtin_bit_cast(V2x2, rw.c3);
    Zr t; t.p0 = v0.lo; t.p1 = v0.hi; t.p2 = v1.lo; t.p3 = v1.hi;
    t.p4 = v2.lo; t.p5 = v2.hi; t.p6 = v3.lo; t.p7 = v3.hi;
    esq[k] = np_sumsq(t);
  }
  if (bx == 0 && tid == 0) {
    out[0] = 0.f;
    out[OFF_OH + 0] = 0.f; out[OFF_OH + 1] = 0.f; out[OFF_OH + 2] = 0.f;
    out[OFF_OH + OH_ELEMS - 1] = 0.f;
  }
  __syncthreads();

  Zr zr0 = load_zr(z + (bbase + q * 4 + 0) * DIMD + n * ED);
  Zr zr1 = load_zr(z + (bbase + q * 4 + 1) * DIMD + n * ED);
  Zr zr2 = load_zr(z + (bbase + q * 4 + 2) * DIMD + n * ED);
  Zr zr3 = load_zr(z + (bbase + q * 4 + 3) * DIMD + n * ED);

  const int gtid = bx * 256 + tid;
  float4* f4 = (float4*)(out + OFF_OH + 3);
  int s = 0, fcnt = 0;

  const int kbeg = part * 256, kend = kbeg + 256;
  const int kmid = (kend < KLDS) ? kend : KLDS;
  const int gbeg = (kbeg > KLDS) ? kbeg : KLDS;
  int bf0 = 0, bf1 = 0, bf2 = 0, bf3 = 0;

  for (int dep = 0; dep < 3; ++dep) {
    const float zs0 = np_sumsq(zr0), zs1 = np_sumsq(zr1);
    const float zs2 = np_sumsq(zr2), zs3 = np_sumsq(zr3);
    float mA0 = 3.0e38f, mA1 = 3.0e38f, mA2 = 3.0e38f, mA3 = 3.0e38f;
    // ---- pass A: pure min (with interleaved onehot zero-fill) ----
    for (int k = kbeg; k < kmid; ++k) {
      if (fcnt == 0) {
        fcnt = 3;
        if (s < 256) {
          int slot = s * 131072 + gtid; ++s;
          if (slot < F4N) f4[slot] = make_float4(0.f, 0.f, 0.f, 0.f);
        }
      }
      --fcnt;
      const float4* cp = (const float4*)(cb + k * 16);
      Row rw; rw.c0 = cp[0]; rw.c1 = cp[1]; rw.c2 = cp[2]; rw.c3 = cp[3];
      const float eh = 0.5f * esq[k];
      mA0 = fminf(mA0, fastv(zr0, rw, eh));
      mA1 = fminf(mA1, fastv(zr1, rw, eh));
      mA2 = fminf(mA2, fastv(zr2, rw, eh));
      mA3 = fminf(mA3, fastv(zr3, rw, eh));
    }
    for (int k = gbeg; k < kend; ++k) {
      if (fcnt == 0) {
        fcnt = 3;
        if (s < 256) {
          int slot = s * 131072 + gtid; ++s;
          if (slot < F4N) f4[slot] = make_float4(0.f, 0.f, 0.f, 0.f);
        }
      }
      --fcnt;
      const float4* cp = (const float4*)(embn + k * 16);
      Row rw; rw.c0 = cp[0]; rw.c1 = cp[1]; rw.c2 = cp[2]; rw.c3 = cp[3];
      const float eh = 0.5f * esq[k];
      mA0 = fminf(mA0, fastv(zr0, rw, eh));
      mA1 = fminf(mA1, fastv(zr1, rw, eh));
      mA2 = fminf(mA2, fastv(zr2, rw, eh));
      mA3 = fminf(mA3, fastv(zr3, rw, eh));
    }
    const float th0 = mA0 + WEPS, th1 = mA1 + WEPS;
    const float th2 = mA2 + WEPS, th3 = mA3 + WEPS;
    // ---- pass B: ref-rounded re-eval only inside the window ----
    float dm0 = 3.0e38f, dm1 = 3.0e38f, dm2 = 3.0e38f, dm3 = 3.0e38f;
    int ki0 = kend - 1, ki1 = kend - 1, ki2 = kend - 1, ki3 = kend - 1;
    for (int k = kbeg; k < kmid; ++k) {
      const float4* cp = (const float4*)(cb + k * 16);
      Row rw; rw.c0 = cp[0]; rw.c1 = cp[1]; rw.c2 = cp[2]; rw.c3 = cp[3];
      const float es = esq[k];
      const float eh = 0.5f * es;
      if (fastv(zr0, rw, eh) < th0) {
        float d = ref_d(zr0, rw, zs0, es);
        if (d < dm0) { dm0 = d; ki0 = k; }
      }
      if (fastv(zr1, rw, eh) < th1) {
        float d = ref_d(zr1, rw, zs1, es);
        if (d < dm1) { dm1 = d; ki1 = k; }
      }
      if (fastv(zr2, rw, eh) < th2) {
        float d = ref_d(zr2, rw, zs2, es);
        if (d < dm2) { dm2 = d; ki2 = k; }
      }
      if (fastv(zr3, rw, eh) < th3) {
        float d = ref_d(zr3, rw, zs3, es);
        if (d < dm3) { dm3 = d; ki3 = k; }
      }
    }
    for (int k = gbeg; k < kend; ++k) {
      const float4* cp = (const float4*)(embn + k * 16);
      Row rw; rw.c0 = cp[0]; rw.c1 = cp[1]; rw.c2 = cp[2]; rw.c3 = cp[3];
      const float es = esq[k];
      const float eh = 0.5f * es;
      if (fastv(zr0, rw, eh) < th0) {
        float d = ref_d(zr0, rw, zs0, es);
        if (d < dm0) { dm0 = d; ki0 = k; }
      }
      if (fastv(zr1, rw, eh) < th1) {
        float d = ref_d(zr1, rw, zs1, es);
        if (d < dm1) { dm1 = d; ki1 = k; }
      }
      if (fastv(zr2, rw, eh) < th2) {
        float d = ref_d(zr2, rw, zs2, es);
        if (d < dm2) { dm2 = d; ki2 = k; }
      }
      if (fastv(zr3, rw, eh) < th3) {
        float d = ref_d(zr3, rw, zs3, es);
        if (d < dm3) { dm3 = d; ki3 = k; }
      }
    }
    // ---- cross-part merge: lexicographic (d_bits, k) min == first-index ----
    mrg[(q * 4 + 0) * PARTS + part] =
        ((unsigned long long)__float_as_uint(dm0) << 32) | (unsigned)ki0;
    mrg[(q * 4 + 1) * PARTS + part] =
        ((unsigned long long)__float_as_uint(dm1) << 32) | (unsigned)ki1;
    mrg[(q * 4 + 2) * PARTS + part] =
        ((unsigned long long)__float_as_uint(dm2) << 32) | (unsigned)ki2;
    mrg[(q * 4 + 3) * PARTS + part] =
        ((unsigned long long)__float_as_uint(dm3) << 32) | (unsigned)ki3;
    __syncthreads();
#define MERGE_R(R, ZR, BF)                                                    \
    {                                                                         \
      const unsigned long long* mp = &mrg[(q * 4 + R) * PARTS];               \
      unsigned long long mb = mp[0];                                          \
      if (mp[1] < mb) mb = mp[1];                                             \
      if (mp[2] < mb) mb = mp[2];                                             \
      if (mp[3] < mb) mb = mp[3];                                             \
      int bi = (int)(mb & 0xffffffffull);                                     \
      BF = bi;                                                                \
      const float4* sp = (bi < KLDS) ? (const float4*)(cb + bi * 16)          \
                                     : (const float4*)(embn + bi * 16);       \
      Row rw; rw.c0 = sp[0]; rw.c1 = sp[1]; rw.c2 = sp[2]; rw.c3 = sp[3];     \
      ZR = sub_row(ZR, rw);                                                   \
    }
    MERGE_R(0, zr0, bf0)
    MERGE_R(1, zr1, bf1)
    MERGE_R(2, zr2, bf2)
    MERGE_R(3, zr3, bf3)
#undef MERGE_R
    __syncthreads();   // protect mrg reuse next depth
  }
  for (; s < 256; ++s) {                 // flush fill quota (safety)
    int slot = s * 131072 + gtid;
    if (slot < F4N) f4[slot] = make_float4(0.f, 0.f, 0.f, 0.f);
  }
  // part 0 writes idx + mean(q) = (z_orig - zf_final)/3 (within ~1e-6 of ref)
  if (part == 0) {
#define WRITE_R(R, ZR, BF)                                                    \
    {                                                                         \
      const int b = bbase + q * 4 + R;                                        \
      out[OFF_IDX + b * NSUB + n] = (float)BF;                                \
      Zr zo = load_zr(z + b * DIMD + n * ED);                                 \
      float* mp2 = out + OFF_ZQ + b * DIMD + n * ED;                          \
      mp2[0]  = __fdiv_rn(__fsub_rn(zo.p0.x, ZR.p0.x), 3.0f);                 \
      mp2[1]  = __fdiv_rn(__fsub_rn(zo.p0.y, ZR.p0.y), 3.0f);                 \
      mp2[2]  = __fdiv_rn(__fsub_rn(zo.p1.x, ZR.p1.x), 3.0f);                 \
      mp2[3]  = __fdiv_rn(__fsub_rn(zo.p1.y, ZR.p1.y), 3.0f);                 \
      mp2[4]  = __fdiv_rn(__fsub_rn(zo.p2.x, ZR.p2.x), 3.0f);                 \
      mp2[5]  = __fdiv_rn(__fsub_rn(zo.p2.y, ZR.p2.y), 3.0f);                 \
      mp2[6]  = __fdiv_rn(__fsub_rn(zo.p3.x, ZR.p3.x), 3.0f);                 \
      mp2[7]  = __fdiv_rn(__fsub_rn(zo.p3.y, ZR.p3.y), 3.0f);                 \
      mp2[8]  = __fdiv_rn(__fsub_rn(zo.p4.x, ZR.p4.x), 3.0f);                 \
      mp2[9]  = __fdiv_rn(__fsub_rn(zo.p4.y, ZR.p4.y), 3.0f);                 \
      mp2[10] = __fdiv_rn(__fsub_rn(zo.p5.x, ZR.p5.x), 3.0f);                 \
      mp2[11] = __fdiv_rn(__fsub_rn(zo.p5.y, ZR.p5.y), 3.0f);                 \
      mp2[12] = __fdiv_rn(__fsub_rn(zo.p6.x, ZR.p6.x), 3.0f);                 \
      mp2[13] = __fdiv_rn(__fsub_rn(zo.p6.y, ZR.p6.y), 3.0f);                 \
      mp2[14] = __fdiv_rn(__fsub_rn(zo.p7.x, ZR.p7.x), 3.0f);                 \
      mp2[15] = __fdiv_rn(__fsub_rn(zo.p7.y, ZR.p7.y), 3.0f);                 \
    }
    WRITE_R(0, zr0, bf0)
    WRITE_R(1, zr1, bf1)
    WRITE_R(2, zr2, bf2)
    WRITE_R(3, zr3, bf3)
#undef WRITE_R
  }
}

// ---------------------------------------------------------------------------
// Kernel 2: scatter the ones into the (already zeroed) onehot region.
// ---------------------------------------------------------------------------
__global__ void vq_ones(float* __restrict__ out) {
  int g = blockIdx.x * 256 + threadIdx.x;          // 0 .. 131071 == b*16+n
  int k = (int)out[OFF_IDX + g];
  out[OFF_OH + g * KC + k] = 1.0f;
}

// ---------------------------------------------------------------------------
// Kernel 3: z_q = mean @ W + b, straight-through output, loss.
// ---------------------------------------------------------------------------
#define TB 16
__global__ __launch_bounds__(256, 2) void vq_head(
    const float* __restrict__ z, const float* __restrict__ W,
    const float* __restrict__ bias, float* __restrict__ out) {
  __shared__ float ml[TB][DIMD];   // 16KB
  __shared__ double reds[4];
  const int t  = threadIdx.x;
  const int r0 = blockIdx.x * TB;
  for (int j = t; j < TB * DIMD; j += 256) {
    int r = j >> 8, d = j & 255;
    ml[r][d] = out[OFF_ZQ + (r0 + r) * DIMD + d];
  }
  __syncthreads();
  float acc[TB];
#pragma unroll
  for (int r = 0; r < TB; ++r) acc[r] = 0.f;
  for (int d = 0; d < DIMD; ++d) {
    float w = W[d * DIMD + t];
#pragma unroll
    for (int r = 0; r < TB; ++r) acc[r] = fmaf(ml[r][d], w, acc[r]);
  }
  const float bv = bias[t];
  double lp = 0.0;
#pragma unroll
  for (int r = 0; r < TB; ++r) {
    float zq   = acc[r] + bv;
    float zv   = z[(r0 + r) * DIMD + t];
    float diff = zq - zv;
    out[OFF_ZQ + (r0 + r) * DIMD + t] = zv + diff;
    lp += (double)diff * (double)diff;
  }
#pragma unroll
  for (int o = 32; o > 0; o >>= 1) lp += __shfl_down(lp, o);
  if ((t & 63) == 0) reds[t >> 6] = lp;
  __syncthreads();
  if (t == 0) {
    double tot = reds[0] + reds[1] + reds[2] + reds[3];
    atomicAdd(out, (float)(tot * (1.25 / (double)(BQ * DIMD))));
  }
}

extern "C" void kernel_launch(void* const* d_in, const int* in_sizes, int n_in,
                              void* d_out, int out_size, void* d_ws, size_t ws_size,
                              hipStream_t stream) {
  const float* z    = (const float*)d_in[0];
  const float* emb  = (const float*)d_in[1];
  const float* W    = (const float*)d_in[2];
  const float* bias = (const float*)d_in[3];
  float* out = (float*)d_out;
  vq_main<<<dim3((BQ / 256) * NSUB), dim3(256), 0, stream>>>(z, emb, out);
  vq_ones<<<dim3((BQ * NSUB) / 256), dim3(256), 0, stream>>>(out);
  vq_head<<<dim3(BQ / TB), dim3(256), 0, stream>>>(z, W, bias, out);
}

// Round 6
// 1063.814 us; speedup vs baseline: 1.0337x; 1.0337x over previous
//
#include <hip/hip_runtime.h>
#include <math.h>

#define BQ    8192
#define DIMD  256
#define NSUB  16
#define KC    1024
#define ED    16
#define KLDS  832          // codebook rows staged in LDS (tail 192 via L1/L2)
#define PARTS 4

#define OFF_ZQ   1
#define OFF_OH   (1 + BQ * DIMD)            // 2097153
#define OH_ELEMS (BQ * NSUB * KC)           // 134217728
#define OFF_IDX  (OFF_OH + OH_ELEMS)        // 136314881
#define F4N      ((OH_ELEMS - 4) / 4)       // aligned float4 slots in onehot
#define WEPS     1e-4f                      // ambiguity window (v-units)

typedef __attribute__((ext_vector_type(2))) float v2f;

struct Zr  { v2f p0, p1, p2, p3, p4, p5, p6, p7; };   // one residual (16 f)
struct Row { float4 c0, c1, c2, c3; };                 // one codebook row
struct V2x2 { v2f lo, hi; };

// fast value: a = eh - sum(z_i*c_i); packed fp32 FMA. |err| <~2e-7 << WEPS.
__device__ __forceinline__ float fastv(Zr z, Row rw, float eh) {
  V2x2 a0 = __builtin_bit_cast(V2x2, rw.c0);
  V2x2 a1 = __builtin_bit_cast(V2x2, rw.c1);
  V2x2 a2 = __builtin_bit_cast(V2x2, rw.c2);
  V2x2 a3 = __builtin_bit_cast(V2x2, rw.c3);
  v2f accA = {eh, 0.f}, accB = {0.f, 0.f};
  accA = __builtin_elementwise_fma(-z.p0, a0.lo, accA);
  accB = __builtin_elementwise_fma(-z.p1, a0.hi, accB);
  accA = __builtin_elementwise_fma(-z.p2, a1.lo, accA);
  accB = __builtin_elementwise_fma(-z.p3, a1.hi, accB);
  accA = __builtin_elementwise_fma(-z.p4, a2.lo, accA);
  accB = __builtin_elementwise_fma(-z.p5, a2.hi, accB);
  accA = __builtin_elementwise_fma(-z.p6, a3.lo, accA);
  accB = __builtin_elementwise_fma(-z.p7, a3.hi, accB);
  v2f acc = accA + accB;
  return acc.x + acc.y;
}

// numpy pairwise sum-of-squares (verified R3).
__device__ __forceinline__ float np_sumsq(Zr z) {
  float q0 = __fmul_rn(z.p0.x, z.p0.x), q1 = __fmul_rn(z.p0.y, z.p0.y);
  float q2 = __fmul_rn(z.p1.x, z.p1.x), q3 = __fmul_rn(z.p1.y, z.p1.y);
  float q4 = __fmul_rn(z.p2.x, z.p2.x), q5 = __fmul_rn(z.p2.y, z.p2.y);
  float q6 = __fmul_rn(z.p3.x, z.p3.x), q7 = __fmul_rn(z.p3.y, z.p3.y);
  float q8 = __fmul_rn(z.p4.x, z.p4.x), q9 = __fmul_rn(z.p4.y, z.p4.y);
  float qa = __fmul_rn(z.p5.x, z.p5.x), qb = __fmul_rn(z.p5.y, z.p5.y);
  float qc = __fmul_rn(z.p6.x, z.p6.x), qd = __fmul_rn(z.p6.y, z.p6.y);
  float qe = __fmul_rn(z.p7.x, z.p7.x), qf = __fmul_rn(z.p7.y, z.p7.y);
  float r0 = __fadd_rn(q0, q8), r1 = __fadd_rn(q1, q9);
  float r2 = __fadd_rn(q2, qa), r3 = __fadd_rn(q3, qb);
  float r4 = __fadd_rn(q4, qc), r5 = __fadd_rn(q5, qd);
  float r6 = __fadd_rn(q6, qe), r7 = __fadd_rn(q7, qf);
  return __fadd_rn(__fadd_rn(__fadd_rn(r0, r1), __fadd_rn(r2, r3)),
                   __fadd_rn(__fadd_rn(r4, r5), __fadd_rn(r6, r7)));
}

// Reference-rounded distance (verified R3): SSE-lane einsum SOP + hadd,
// step-rounded d^2 assembly, fp64 sqrt (correctly rounded, CPU-bit-exact).
__device__ __forceinline__ float ref_d(Zr z, Row rw, float zsq, float esq) {
  float p0  = __fmul_rn(z.p0.x, rw.c0.x), p1  = __fmul_rn(z.p0.y, rw.c0.y);
  float p2  = __fmul_rn(z.p1.x, rw.c0.z), p3  = __fmul_rn(z.p1.y, rw.c0.w);
  float p4  = __fmul_rn(z.p2.x, rw.c1.x), p5  = __fmul_rn(z.p2.y, rw.c1.y);
  float p6  = __fmul_rn(z.p3.x, rw.c1.z), p7  = __fmul_rn(z.p3.y, rw.c1.w);
  float p8  = __fmul_rn(z.p4.x, rw.c2.x), p9  = __fmul_rn(z.p4.y, rw.c2.y);
  float p10 = __fmul_rn(z.p5.x, rw.c2.z), p11 = __fmul_rn(z.p5.y, rw.c2.w);
  float p12 = __fmul_rn(z.p6.x, rw.c3.x), p13 = __fmul_rn(z.p6.y, rw.c3.y);
  float p14 = __fmul_rn(z.p7.x, rw.c3.z), p15 = __fmul_rn(z.p7.y, rw.c3.w);
  float L0 = __fadd_rn(__fadd_rn(__fadd_rn(p0, p4), p8),  p12);
  float L1 = __fadd_rn(__fadd_rn(__fadd_rn(p1, p5), p9),  p13);
  float L2 = __fadd_rn(__fadd_rn(__fadd_rn(p2, p6), p10), p14);
  float L3 = __fadd_rn(__fadd_rn(__fadd_rn(p3, p7), p11), p15);
  float cross = __fadd_rn(__fadd_rn(L0, L1), __fadd_rn(L2, L3));
  float t = __fsub_rn(zsq, __fmul_rn(2.0f, cross));
  t = __fadd_rn(t, esq);
  t = fmaxf(t, 0.0f);
  return (float)sqrt((double)t);
}

__device__ __forceinline__ Zr sub_row(Zr z, Row rw) {   // elementwise __fsub_rn
  Zr o;
  o.p0 = (v2f){__fsub_rn(z.p0.x, rw.c0.x), __fsub_rn(z.p0.y, rw.c0.y)};
  o.p1 = (v2f){__fsub_rn(z.p1.x, rw.c0.z), __fsub_rn(z.p1.y, rw.c0.w)};
  o.p2 = (v2f){__fsub_rn(z.p2.x, rw.c1.x), __fsub_rn(z.p2.y, rw.c1.y)};
  o.p3 = (v2f){__fsub_rn(z.p3.x, rw.c1.z), __fsub_rn(z.p3.y, rw.c1.w)};
  o.p4 = (v2f){__fsub_rn(z.p4.x, rw.c2.x), __fsub_rn(z.p4.y, rw.c2.y)};
  o.p5 = (v2f){__fsub_rn(z.p5.x, rw.c2.z), __fsub_rn(z.p5.y, rw.c2.w)};
  o.p6 = (v2f){__fsub_rn(z.p6.x, rw.c3.x), __fsub_rn(z.p6.y, rw.c3.y)};
  o.p7 = (v2f){__fsub_rn(z.p7.x, rw.c3.z), __fsub_rn(z.p7.y, rw.c3.w)};
  return o;
}

__device__ __forceinline__ Zr load_zr(const float* p) {
  const float4* zp = (const float4*)p;
  float4 a0 = zp[0], a1 = zp[1], a2 = zp[2], a3 = zp[3];
  V2x2 v0 = __builtin_bit_cast(V2x2, a0), v1 = __builtin_bit_cast(V2x2, a1);
  V2x2 v2 = __builtin_bit_cast(V2x2, a2), v3 = __builtin_bit_cast(V2x2, a3);
  Zr z;
  z.p0 = v0.lo; z.p1 = v0.hi; z.p2 = v1.lo; z.p3 = v1.hi;
  z.p4 = v2.lo; z.p5 = v2.hi; z.p6 = v3.lo; z.p7 = v3.hi;
  return z;
}

__device__ __forceinline__ Row load_row(const float* p) {
  const float4* cp = (const float4*)p;
  Row rw; rw.c0 = cp[0]; rw.c1 = cp[1]; rw.c2 = cp[2]; rw.c3 = cp[3];
  return rw;
}

// ---------------------------------------------------------------------------
// Kernel 1: block = 256 scans x 1 n; thread = 4 scans x 1/4 of k-range.
// Single fast scan tracking (m1,k1,m2); merged gap >= WEPS => fast argmin ==
// reference argmin (no ref_d at all). Rare gap<WEPS scans take an exact
// ref-rounded fallback rescan. Onehot zero-fill interleaved with the scan.
// ---------------------------------------------------------------------------
__global__ __launch_bounds__(256, 2) void vq_main(
    const float* __restrict__ z, const float* __restrict__ emb,
    float* __restrict__ out) {
  __shared__ float cb[KLDS * ED];   // 53248 B
  __shared__ float esq[KC];         // 4096 B
  __shared__ float mV[256 * 2];     // 2048 B  merge: value
  __shared__ int   mK[256 * 2];     // 2048 B  merge: k
  __shared__ float mM[256 * 2];     // 2048 B  merge: second-min (63488 total)
  const int tid   = threadIdx.x;
  const int bx    = blockIdx.x;
  const int n     = bx & 15;
  const int bbase = (bx >> 4) * 256;
  const int part  = tid >> 6;          // wave id: k-range wave-uniform
  const int q     = tid & 63;
  const float* embn = emb + n * (KC * ED);

  {
    const float4* src = (const float4*)embn;
    float4* dst = (float4*)cb;
    for (int i = tid; i < KLDS * ED / 4; i += 256) dst[i] = src[i];
  }
  __syncthreads();
  for (int k = tid; k < KC; k += 256) {
    const float* cr = (k < KLDS) ? (cb + k * 16) : (embn + k * 16);
    Row rw = load_row(cr);
    V2x2 v0 = __builtin_bit_cast(V2x2, rw.c0), v1 = __builtin_bit_cast(V2x2, rw.c1);
    V2x2 v2 = __builtin_bit_cast(V2x2, rw.c2), v3 = __builtin_bit_cast(V2x2, rw.c3);
    Zr t; t.p0 = v0.lo; t.p1 = v0.hi; t.p2 = v1.lo; t.p3 = v1.hi;
    t.p4 = v2.lo; t.p5 = v2.hi; t.p6 = v3.lo; t.p7 = v3.hi;
    esq[k] = np_sumsq(t);
  }
  if (bx == 0 && tid == 0) {
    out[0] = 0.f;
    out[OFF_OH + 0] = 0.f; out[OFF_OH + 1] = 0.f; out[OFF_OH + 2] = 0.f;
    out[OFF_OH + OH_ELEMS - 1] = 0.f;
  }
  __syncthreads();

  Zr zr0 = load_zr(z + (bbase + q * 4 + 0) * DIMD + n * ED);
  Zr zr1 = load_zr(z + (bbase + q * 4 + 1) * DIMD + n * ED);
  Zr zr2 = load_zr(z + (bbase + q * 4 + 2) * DIMD + n * ED);
  Zr zr3 = load_zr(z + (bbase + q * 4 + 3) * DIMD + n * ED);

  const int gtid = bx * 256 + tid;
  float4* f4 = (float4*)(out + OFF_OH + 3);
  int s = 0, fcnt = 0;

  const int kbeg = part * 256, kend = kbeg + 256;
  const int kmid = (kend < KLDS) ? kend : KLDS;
  const int gbeg = (kbeg > KLDS) ? kbeg : KLDS;
  int bi0 = 0, bi1 = 0, bi2 = 0, bi3 = 0;

  for (int dep = 0; dep < 3; ++dep) {
    const float zs0 = np_sumsq(zr0), zs1 = np_sumsq(zr1);
    const float zs2 = np_sumsq(zr2), zs3 = np_sumsq(zr3);
    float m10 = 3.0e38f, m11 = 3.0e38f, m12 = 3.0e38f, m13 = 3.0e38f;
    float m20 = 3.0e38f, m21 = 3.0e38f, m22 = 3.0e38f, m23 = 3.0e38f;
    int k10 = kbeg, k11 = kbeg, k12 = kbeg, k13 = kbeg;

#define EVAL4                                                                 \
    {                                                                         \
      const float eh = 0.5f * esq[k];                                         \
      float v0x = fastv(zr0, rw, eh);                                         \
      m20 = __builtin_amdgcn_fmed3f(v0x, m10, m20);                           \
      bool l0 = v0x < m10; m10 = l0 ? v0x : m10; k10 = l0 ? k : k10;          \
      float v1x = fastv(zr1, rw, eh);                                         \
      m21 = __builtin_amdgcn_fmed3f(v1x, m11, m21);                           \
      bool l1 = v1x < m11; m11 = l1 ? v1x : m11; k11 = l1 ? k : k11;          \
      float v2x = fastv(zr2, rw, eh);                                         \
      m22 = __builtin_amdgcn_fmed3f(v2x, m12, m22);                           \
      bool l2 = v2x < m12; m12 = l2 ? v2x : m12; k12 = l2 ? k : k12;          \
      float v3x = fastv(zr3, rw, eh);                                         \
      m23 = __builtin_amdgcn_fmed3f(v3x, m13, m23);                           \
      bool l3 = v3x < m13; m13 = l3 ? v3x : m13; k13 = l3 ? k : k13;          \
    }
#define FILLSTORE                                                             \
    if (fcnt == 0) {                                                          \
      fcnt = 3;                                                               \
      if (s < 256) {                                                          \
        int slot = s * 131072 + gtid; ++s;                                    \
        if (slot < F4N) f4[slot] = make_float4(0.f, 0.f, 0.f, 0.f);           \
      }                                                                       \
    }                                                                         \
    --fcnt;

    for (int k = kbeg; k < kmid; ++k) {         // LDS rows
      FILLSTORE
      Row rw = load_row(cb + k * 16);
      EVAL4
    }
    for (int k = gbeg; k < kend; ++k) {         // global tail (L1/L2-hot)
      FILLSTORE
      Row rw = load_row(embn + k * 16);
      EVAL4
    }
#undef EVAL4
#undef FILLSTORE

    // ---- merge (m1,k1,m2) across parts: {0,2} and {1,3}, then combine ----
    if (part < 2) {
#define ST(R, M1, K1, M2)                                                     \
      { int sl = (q * 4 + R) * 2 + part; mV[sl] = M1; mK[sl] = K1; mM[sl] = M2; }
      ST(0, m10, k10, m20) ST(1, m11, k11, m21)
      ST(2, m12, k12, m22) ST(3, m13, k13, m23)
#undef ST
    }
    __syncthreads();
    if (part >= 2) {
#define MG(R, M1, K1, M2)                                                     \
      { int sl = (q * 4 + R) * 2 + (part - 2);                                \
        float am1 = mV[sl]; int ak1 = mK[sl]; float am2 = mM[sl];             \
        bool bw = (M1 < am1) || (M1 == am1 && K1 < ak1);                      \
        float nm2 = fminf(bw ? M2 : am2, bw ? am1 : M1);                      \
        mV[sl] = bw ? M1 : am1; mK[sl] = bw ? K1 : ak1; mM[sl] = nm2; }
      MG(0, m10, k10, m20) MG(1, m11, k11, m21)
      MG(2, m12, k12, m22) MG(3, m13, k13, m23)
#undef MG
    }
    __syncthreads();
    float gm0, gm1v, gm2v, gm3v; int gfb;
    bool fb0, fb1, fb2, fb3;
#define RD(R, GM, BI, FB)                                                     \
    { int sl = (q * 4 + R) * 2;                                               \
      float a1 = mV[sl], a2 = mM[sl]; int ak = mK[sl];                        \
      float b1 = mV[sl + 1], b2 = mM[sl + 1]; int bk = mK[sl + 1];            \
      bool bw = (b1 < a1) || (b1 == a1 && bk < ak);                           \
      float w1 = bw ? b1 : a1; int wk = bw ? bk : ak;                         \
      float w2 = fminf(bw ? b2 : a2, bw ? a1 : b1);                           \
      GM = w1; BI = wk; FB = (__fsub_rn(w2, w1) < WEPS); }
    RD(0, gm0, bi0, fb0) RD(1, gm1v, bi1, fb1)
    RD(2, gm2v, bi2, fb2) RD(3, gm3v, bi3, fb3)
#undef RD
    __syncthreads();   // slots quiescent before fallback writes

    // ---- fallback (rare): exact ref-rounded rescan of ambiguous scans ----
    float dm0 = 3.0e38f, dm1 = 3.0e38f, dm2 = 3.0e38f, dm3 = 3.0e38f;
    int km0 = kbeg, km1 = kbeg, km2 = kbeg, km3 = kbeg;
    if (fb0 | fb1 | fb2 | fb3) {
#define FEVAL(R, FB, ZR, ZS, GM, DM, KM)                                      \
      if (FB) {                                                               \
        float v = fastv(ZR, rw, eh);                                          \
        if (v < GM + WEPS) {                                                  \
          float d = ref_d(ZR, rw, ZS, es);                                    \
          if (d < DM) { DM = d; KM = k; }                                     \
        }                                                                     \
      }
      for (int k = kbeg; k < kmid; ++k) {
        Row rw = load_row(cb + k * 16);
        const float es = esq[k]; const float eh = 0.5f * es;
        FEVAL(0, fb0, zr0, zs0, gm0,  dm0, km0)
        FEVAL(1, fb1, zr1, zs1, gm1v, dm1, km1)
        FEVAL(2, fb2, zr2, zs2, gm2v, dm2, km2)
        FEVAL(3, fb3, zr3, zs3, gm3v, dm3, km3)
      }
      for (int k = gbeg; k < kend; ++k) {
        Row rw = load_row(embn + k * 16);
        const float es = esq[k]; const float eh = 0.5f * es;
        FEVAL(0, fb0, zr0, zs0, gm0,  dm0, km0)
        FEVAL(1, fb1, zr1, zs1, gm1v, dm1, km1)
        FEVAL(2, fb2, zr2, zs2, gm2v, dm2, km2)
        FEVAL(3, fb3, zr3, zs3, gm3v, dm3, km3)
      }
#undef FEVAL
    }
    if (part < 2) {
#define FST(R, FB, DM, KM)                                                    \
      if (FB) { int sl = (q * 4 + R) * 2 + part; mV[sl] = DM; mK[sl] = KM; }
      FST(0, fb0, dm0, km0) FST(1, fb1, dm1, km1)
      FST(2, fb2, dm2, km2) FST(3, fb3, dm3, km3)
#undef FST
    }
    __syncthreads();
    if (part >= 2) {
#define FMG(R, FB, DM, KM)                                                    \
      if (FB) { int sl = (q * 4 + R) * 2 + (part - 2);                        \
        float ad = mV[sl]; int ak = mK[sl];                                   \
        bool bw = (DM < ad) || (DM == ad && KM < ak);                         \
        mV[sl] = bw ? DM : ad; mK[sl] = bw ? KM : ak; }
      FMG(0, fb0, dm0, km0) FMG(1, fb1, dm1, km1)
      FMG(2, fb2, dm2, km2) FMG(3, fb3, dm3, km3)
#undef FMG
    }
    __syncthreads();
#define FRD(R, FB, BI)                                                        \
    if (FB) { int sl = (q * 4 + R) * 2;                                       \
      float ad = mV[sl], bd = mV[sl + 1]; int ak = mK[sl], bk = mK[sl + 1];   \
      bool bw = (bd < ad) || (bd == ad && bk < ak);                           \
      BI = bw ? bk : ak; }
    FRD(0, fb0, bi0) FRD(1, fb1, bi1) FRD(2, fb2, bi2) FRD(3, fb3, bi3)
#undef FRD

    // ---- residual update: global row read (L2-hot, identical per co-owner)
    zr0 = sub_row(zr0, load_row(embn + bi0 * 16));
    zr1 = sub_row(zr1, load_row(embn + bi1 * 16));
    zr2 = sub_row(zr2, load_row(embn + bi2 * 16));
    zr3 = sub_row(zr3, load_row(embn + bi3 * 16));
    __syncthreads();   // protect merge arrays for next depth
  }
  for (; s < 256; ++s) {                 // flush fill quota (safety)
    int slot = s * 131072 + gtid;
    if (slot < F4N) f4[slot] = make_float4(0.f, 0.f, 0.f, 0.f);
  }
  // part 0 writes idx + mean(q) = (z_orig - zr_final)/3 (R5-verified path)
  if (part == 0) {
#define WRITE_R(R, ZR, BI)                                                    \
    {                                                                         \
      const int b = bbase + q * 4 + R;                                        \
      out[OFF_IDX + b * NSUB + n] = (float)BI;                                \
      Zr zo = load_zr(z + b * DIMD + n * ED);                                 \
      float* mp2 = out + OFF_ZQ + b * DIMD + n * ED;                          \
      mp2[0]  = __fdiv_rn(__fsub_rn(zo.p0.x, ZR.p0.x), 3.0f);                 \
      mp2[1]  = __fdiv_rn(__fsub_rn(zo.p0.y, ZR.p0.y), 3.0f);                 \
      mp2[2]  = __fdiv_rn(__fsub_rn(zo.p1.x, ZR.p1.x), 3.0f);                 \
      mp2[3]  = __fdiv_rn(__fsub_rn(zo.p1.y, ZR.p1.y), 3.0f);                 \
      mp2[4]  = __fdiv_rn(__fsub_rn(zo.p2.x, ZR.p2.x), 3.0f);                 \
      mp2[5]  = __fdiv_rn(__fsub_rn(zo.p2.y, ZR.p2.y), 3.0f);                 \
      mp2[6]  = __fdiv_rn(__fsub_rn(zo.p3.x, ZR.p3.x), 3.0f);                 \
      mp2[7]  = __fdiv_rn(__fsub_rn(zo.p3.y, ZR.p3.y), 3.0f);                 \
      mp2[8]  = __fdiv_rn(__fsub_rn(zo.p4.x, ZR.p4.x), 3.0f);                 \
      mp2[9]  = __fdiv_rn(__fsub_rn(zo.p4.y, ZR.p4.y), 3.0f);                 \
      mp2[10] = __fdiv_rn(__fsub_rn(zo.p5.x, ZR.p5.x), 3.0f);                 \
      mp2[11] = __fdiv_rn(__fsub_rn(zo.p5.y, ZR.p5.y), 3.0f);                 \
      mp2[12] = __fdiv_rn(__fsub_rn(zo.p6.x, ZR.p6.x), 3.0f);                 \
      mp2[13] = __fdiv_rn(__fsub_rn(zo.p6.y, ZR.p6.y), 3.0f);                 \
      mp2[14] = __fdiv_rn(__fsub_rn(zo.p7.x, ZR.p7.x), 3.0f);                 \
      mp2[15] = __fdiv_rn(__fsub_rn(zo.p7.y, ZR.p7.y), 3.0f);                 \
    }
    WRITE_R(0, zr0, bi0)
    WRITE_R(1, zr1, bi1)
    WRITE_R(2, zr2, bi2)
    WRITE_R(3, zr3, bi3)
#undef WRITE_R
  }
}

// ---------------------------------------------------------------------------
// Kernel 2: scatter the ones into the (already zeroed) onehot region.
// ---------------------------------------------------------------------------
__global__ void vq_ones(float* __restrict__ out) {
  int g = blockIdx.x * 256 + threadIdx.x;          // 0 .. 131071 == b*16+n
  int k = (int)out[OFF_IDX + g];
  out[OFF_OH + g * KC + k] = 1.0f;
}

// ---------------------------------------------------------------------------
// Kernel 3: z_q = mean @ W + b, straight-through output, loss.
// ---------------------------------------------------------------------------
#define TB 16
__global__ __launch_bounds__(256, 2) void vq_head(
    const float* __restrict__ z, const float* __restrict__ W,
    const float* __restrict__ bias, float* __restrict__ out) {
  __shared__ float ml[TB][DIMD];   // 16KB
  __shared__ double reds[4];
  const int t  = threadIdx.x;
  const int r0 = blockIdx.x * TB;
  for (int j = t; j < TB * DIMD; j += 256) {
    int r = j >> 8, d = j & 255;
    ml[r][d] = out[OFF_ZQ + (r0 + r) * DIMD + d];
  }
  __syncthreads();
  float acc[TB];
#pragma unroll
  for (int r = 0; r < TB; ++r) acc[r] = 0.f;
  for (int d = 0; d < DIMD; ++d) {
    float w = W[d * DIMD + t];
#pragma unroll
    for (int r = 0; r < TB; ++r) acc[r] = fmaf(ml[r][d], w, acc[r]);
  }
  const float bv = bias[t];
  double lp = 0.0;
#pragma unroll
  for (int r = 0; r < TB; ++r) {
    float zq   = acc[r] + bv;
    float zv   = z[(r0 + r) * DIMD + t];
    float diff = zq - zv;
    out[OFF_ZQ + (r0 + r) * DIMD + t] = zv + diff;
    lp += (double)diff * (double)diff;
  }
#pragma unroll
  for (int o = 32; o > 0; o >>= 1) lp += __shfl_down(lp, o);
  if ((t & 63) == 0) reds[t >> 6] = lp;
  __syncthreads();
  if (t == 0) {
    double tot = reds[0] + reds[1] + reds[2] + reds[3];
    atomicAdd(out, (float)(tot * (1.25 / (double)(BQ * DIMD))));
  }
}

extern "C" void kernel_launch(void* const* d_in, const int* in_sizes, int n_in,
                              void* d_out, int out_size, void* d_ws, size_t ws_size,
                              hipStream_t stream) {
  const float* z    = (const float*)d_in[0];
  const float* emb  = (const float*)d_in[1];
  const float* W    = (const float*)d_in[2];
  const float* bias = (const float*)d_in[3];
  float* out = (float*)d_out;
  vq_main<<<dim3((BQ / 256) * NSUB), dim3(256), 0, stream>>>(z, emb, out);
  vq_ones<<<dim3((BQ * NSUB) / 256), dim3(256), 0, stream>>>(out);
  vq_head<<<dim3(BQ / TB), dim3(256), 0, stream>>>(z, W, bias, out);
}

// Round 7
// 709.080 us; speedup vs baseline: 1.5508x; 1.5003x over previous
//
#include <hip/hip_runtime.h>
#include <math.h>

#define BQ    8192
#define DIMD  256
#define NSUB  16
#define KC    1024
#define ED    16

#define OFF_ZQ   1
#define OFF_OH   (1 + BQ * DIMD)            // 2097153
#define OH_ELEMS (BQ * NSUB * KC)           // 134217728
#define OFF_IDX  (OFF_OH + OH_ELEMS)        // 136314881
#define F4N      ((OH_ELEMS - 4) / 4)       // aligned float4 slots in onehot
#define WEPS     2e-4f                      // ambiguity window (v-units)

typedef __attribute__((ext_vector_type(2))) float v2f;
typedef __attribute__((ext_vector_type(4))) float f32x4;
typedef __attribute__((ext_vector_type(8))) short bshort8;   // 8 bf16 (guide §3)
typedef __attribute__((ext_vector_type(4))) unsigned int u32x4;

struct Zr  { v2f p0, p1, p2, p3, p4, p5, p6, p7; };   // one residual (16 f)
struct Row { float4 c0, c1, c2, c3; };                 // one codebook row
struct V2x2 { v2f lo, hi; };

// numpy pairwise sum-of-squares (verified R3).
__device__ __forceinline__ float np_sumsq(Zr z) {
  float q0 = __fmul_rn(z.p0.x, z.p0.x), q1 = __fmul_rn(z.p0.y, z.p0.y);
  float q2 = __fmul_rn(z.p1.x, z.p1.x), q3 = __fmul_rn(z.p1.y, z.p1.y);
  float q4 = __fmul_rn(z.p2.x, z.p2.x), q5 = __fmul_rn(z.p2.y, z.p2.y);
  float q6 = __fmul_rn(z.p3.x, z.p3.x), q7 = __fmul_rn(z.p3.y, z.p3.y);
  float q8 = __fmul_rn(z.p4.x, z.p4.x), q9 = __fmul_rn(z.p4.y, z.p4.y);
  float qa = __fmul_rn(z.p5.x, z.p5.x), qb = __fmul_rn(z.p5.y, z.p5.y);
  float qc = __fmul_rn(z.p6.x, z.p6.x), qd = __fmul_rn(z.p6.y, z.p6.y);
  float qe = __fmul_rn(z.p7.x, z.p7.x), qf = __fmul_rn(z.p7.y, z.p7.y);
  float r0 = __fadd_rn(q0, q8), r1 = __fadd_rn(q1, q9);
  float r2 = __fadd_rn(q2, qa), r3 = __fadd_rn(q3, qb);
  float r4 = __fadd_rn(q4, qc), r5 = __fadd_rn(q5, qd);
  float r6 = __fadd_rn(q6, qe), r7 = __fadd_rn(q7, qf);
  return __fadd_rn(__fadd_rn(__fadd_rn(r0, r1), __fadd_rn(r2, r3)),
                   __fadd_rn(__fadd_rn(r4, r5), __fadd_rn(r6, r7)));
}

// Reference-rounded distance (verified R3): SSE-lane einsum SOP + hadd,
// step-rounded d^2 assembly, fp64 sqrt (correctly rounded, CPU-bit-exact).
__device__ __forceinline__ float ref_d(Zr z, Row rw, float zsq, float esq) {
  float p0  = __fmul_rn(z.p0.x, rw.c0.x), p1  = __fmul_rn(z.p0.y, rw.c0.y);
  float p2  = __fmul_rn(z.p1.x, rw.c0.z), p3  = __fmul_rn(z.p1.y, rw.c0.w);
  float p4  = __fmul_rn(z.p2.x, rw.c1.x), p5  = __fmul_rn(z.p2.y, rw.c1.y);
  float p6  = __fmul_rn(z.p3.x, rw.c1.z), p7  = __fmul_rn(z.p3.y, rw.c1.w);
  float p8  = __fmul_rn(z.p4.x, rw.c2.x), p9  = __fmul_rn(z.p4.y, rw.c2.y);
  float p10 = __fmul_rn(z.p5.x, rw.c2.z), p11 = __fmul_rn(z.p5.y, rw.c2.w);
  float p12 = __fmul_rn(z.p6.x, rw.c3.x), p13 = __fmul_rn(z.p6.y, rw.c3.y);
  float p14 = __fmul_rn(z.p7.x, rw.c3.z), p15 = __fmul_rn(z.p7.y, rw.c3.w);
  float L0 = __fadd_rn(__fadd_rn(__fadd_rn(p0, p4), p8),  p12);
  float L1 = __fadd_rn(__fadd_rn(__fadd_rn(p1, p5), p9),  p13);
  float L2 = __fadd_rn(__fadd_rn(__fadd_rn(p2, p6), p10), p14);
  float L3 = __fadd_rn(__fadd_rn(__fadd_rn(p3, p7), p11), p15);
  float cross = __fadd_rn(__fadd_rn(L0, L1), __fadd_rn(L2, L3));
  float t = __fsub_rn(zsq, __fmul_rn(2.0f, cross));
  t = __fadd_rn(t, esq);
  t = fmaxf(t, 0.0f);
  return (float)sqrt((double)t);
}

__device__ __forceinline__ Zr sub_row(Zr z, Row rw) {   // elementwise __fsub_rn
  Zr o;
  o.p0 = (v2f){__fsub_rn(z.p0.x, rw.c0.x), __fsub_rn(z.p0.y, rw.c0.y)};
  o.p1 = (v2f){__fsub_rn(z.p1.x, rw.c0.z), __fsub_rn(z.p1.y, rw.c0.w)};
  o.p2 = (v2f){__fsub_rn(z.p2.x, rw.c1.x), __fsub_rn(z.p2.y, rw.c1.y)};
  o.p3 = (v2f){__fsub_rn(z.p3.x, rw.c1.z), __fsub_rn(z.p3.y, rw.c1.w)};
  o.p4 = (v2f){__fsub_rn(z.p4.x, rw.c2.x), __fsub_rn(z.p4.y, rw.c2.y)};
  o.p5 = (v2f){__fsub_rn(z.p5.x, rw.c2.z), __fsub_rn(z.p5.y, rw.c2.w)};
  o.p6 = (v2f){__fsub_rn(z.p6.x, rw.c3.x), __fsub_rn(z.p6.y, rw.c3.y)};
  o.p7 = (v2f){__fsub_rn(z.p7.x, rw.c3.z), __fsub_rn(z.p7.y, rw.c3.w)};
  return o;
}

__device__ __forceinline__ Zr load_zr(const float* p) {
  const float4* zp = (const float4*)p;
  float4 a0 = zp[0], a1 = zp[1], a2 = zp[2], a3 = zp[3];
  V2x2 v0 = __builtin_bit_cast(V2x2, a0), v1 = __builtin_bit_cast(V2x2, a1);
  V2x2 v2 = __builtin_bit_cast(V2x2, a2), v3 = __builtin_bit_cast(V2x2, a3);
  Zr z;
  z.p0 = v0.lo; z.p1 = v0.hi; z.p2 = v1.lo; z.p3 = v1.hi;
  z.p4 = v2.lo; z.p5 = v2.hi; z.p6 = v3.lo; z.p7 = v3.hi;
  return z;
}

__device__ __forceinline__ Row load_row(const float* p) {
  const float4* cp = (const float4*)p;
  Row rw; rw.c0 = cp[0]; rw.c1 = cp[1]; rw.c2 = cp[2]; rw.c3 = cp[3];
  return rw;
}

// fp32 -> bf16 (RNE) and back; fast-path only (window absorbs any mode diff).
__device__ __forceinline__ unsigned int f2bf(float x) {
  unsigned int u = __float_as_uint(x);
  return (u + 0x7FFFu + ((u >> 16) & 1u)) >> 16;
}
__device__ __forceinline__ float bf2f(unsigned int b) {
  return __uint_as_float(b << 16);
}

// ---------------------------------------------------------------------------
// Prep: split-negate codebook into ws: per code row 64B = [bf16 hi(-c) x16 |
// bf16 lo(-c) x16], chunk q (16B) == elements [q*8, q*8+8) of the 32-vector.
// ---------------------------------------------------------------------------
__global__ void vq_prep(const float* __restrict__ emb,
                        unsigned int* __restrict__ ws) {
  const int row = blockIdx.x * 256 + threadIdx.x;   // 16384 rows (n*1024+k)
  const float* c = emb + row * 16;
  unsigned int o[16];
#pragma unroll
  for (int u = 0; u < 8; ++u) {
    float a = -c[2 * u], b = -c[2 * u + 1];
    unsigned int h0 = f2bf(a), h1 = f2bf(b);
    o[u] = h0 | (h1 << 16);
    unsigned int l0 = f2bf(__fsub_rn(a, bf2f(h0)));
    unsigned int l1 = f2bf(__fsub_rn(b, bf2f(h1)));
    o[8 + u] = l0 | (l1 << 16);
  }
  u32x4* dst = (u32x4*)ws + row * 4;
#pragma unroll
  for (int j = 0; j < 4; ++j)
    dst[j] = (u32x4){o[4 * j], o[4 * j + 1], o[4 * j + 2], o[4 * j + 3]};
}

// ---------------------------------------------------------------------------
// Kernel 1: MFMA scan. Block = 256 scans x 1 n; wave = 64 scans x full k.
// Two mfma_f32_16x16x32_bf16 per 16x16 tile implement the full bf16 hi/lo
// split product (fp32-grade fast v). Gap>=WEPS => ref-identical argmin;
// else wave-cooperative exact ref_d rescan (first-index semantics).
// ---------------------------------------------------------------------------
__global__ __launch_bounds__(256, 4) void vq_main(
    const float* __restrict__ z, const float* __restrict__ emb,
    const unsigned int* __restrict__ ws, float* __restrict__ out) {
  __shared__ float esq[KC];                    // 4 KB
  __shared__ float ehs[KC];                    // 4 KB
  __shared__ unsigned int zq[4 * 64 * 16];     // 16 KB bf16-split residuals
  __shared__ float zb[4 * 64 * 16];            // 16 KB fp32 residuals
  const int tid   = threadIdx.x;
  const int bx    = blockIdx.x;
  const int n     = bx & 15;
  const int bbase = (bx >> 4) * 256;
  const int w     = tid >> 6;
  const int lane  = tid & 63;
  const int q     = lane >> 4;
  const int c16   = lane & 15;
  const float* embn = emb + n * (KC * ED);
  const u32x4* wsn  = (const u32x4*)ws + n * (KC * 4);

  for (int k = tid; k < KC; k += 256) {
    float s = np_sumsq(load_zr(embn + k * 16));
    esq[k] = s; ehs[k] = 0.5f * s;
  }
  if (bx == 0 && tid == 0) {
    out[0] = 0.f;
    out[OFF_OH + 0] = 0.f; out[OFF_OH + 1] = 0.f; out[OFF_OH + 2] = 0.f;
    out[OFF_OH + OH_ELEMS - 1] = 0.f;
  }
  __syncthreads();

  const int scanB = bbase + tid;               // this thread's b
  Zr zr = load_zr(z + scanB * DIMD + n * ED);
  unsigned int* zqw = zq + w * 1024;
  float*        zbw = zb + w * 1024;

#define STAGE_ZR                                                              \
  {                                                                           \
    const int o = lane * 16;                                                  \
    v2f* zb2 = (v2f*)(zbw + o);                                               \
    zb2[0]=zr.p0; zb2[1]=zr.p1; zb2[2]=zr.p2; zb2[3]=zr.p3;                   \
    zb2[4]=zr.p4; zb2[5]=zr.p5; zb2[6]=zr.p6; zb2[7]=zr.p7;                   \
    _Pragma("unroll")                                                         \
    for (int u = 0; u < 8; ++u) { }                                           \
    /* pack pairs explicitly */                                               \
    {                                                                         \
      v2f P; unsigned h0, h1, l0, l1;                                         \
      P=zr.p0; h0=f2bf(P.x); h1=f2bf(P.y); zqw[o+0]=h0|(h1<<16);              \
      l0=f2bf(__fsub_rn(P.x,bf2f(h0))); l1=f2bf(__fsub_rn(P.y,bf2f(h1)));     \
      zqw[o+8]=l0|(l1<<16);                                                   \
      P=zr.p1; h0=f2bf(P.x); h1=f2bf(P.y); zqw[o+1]=h0|(h1<<16);              \
      l0=f2bf(__fsub_rn(P.x,bf2f(h0))); l1=f2bf(__fsub_rn(P.y,bf2f(h1)));     \
      zqw[o+9]=l0|(l1<<16);                                                   \
      P=zr.p2; h0=f2bf(P.x); h1=f2bf(P.y); zqw[o+2]=h0|(h1<<16);              \
      l0=f2bf(__fsub_rn(P.x,bf2f(h0))); l1=f2bf(__fsub_rn(P.y,bf2f(h1)));     \
      zqw[o+10]=l0|(l1<<16);                                                  \
      P=zr.p3; h0=f2bf(P.x); h1=f2bf(P.y); zqw[o+3]=h0|(h1<<16);              \
      l0=f2bf(__fsub_rn(P.x,bf2f(h0))); l1=f2bf(__fsub_rn(P.y,bf2f(h1)));     \
      zqw[o+11]=l0|(l1<<16);                                                  \
      P=zr.p4; h0=f2bf(P.x); h1=f2bf(P.y); zqw[o+4]=h0|(h1<<16);              \
      l0=f2bf(__fsub_rn(P.x,bf2f(h0))); l1=f2bf(__fsub_rn(P.y,bf2f(h1)));     \
      zqw[o+12]=l0|(l1<<16);                                                  \
      P=zr.p5; h0=f2bf(P.x); h1=f2bf(P.y); zqw[o+5]=h0|(h1<<16);              \
      l0=f2bf(__fsub_rn(P.x,bf2f(h0))); l1=f2bf(__fsub_rn(P.y,bf2f(h1)));     \
      zqw[o+13]=l0|(l1<<16);                                                  \
      P=zr.p6; h0=f2bf(P.x); h1=f2bf(P.y); zqw[o+6]=h0|(h1<<16);              \
      l0=f2bf(__fsub_rn(P.x,bf2f(h0))); l1=f2bf(__fsub_rn(P.y,bf2f(h1)));     \
      zqw[o+14]=l0|(l1<<16);                                                  \
      P=zr.p7; h0=f2bf(P.x); h1=f2bf(P.y); zqw[o+7]=h0|(h1<<16);              \
      l0=f2bf(__fsub_rn(P.x,bf2f(h0))); l1=f2bf(__fsub_rn(P.y,bf2f(h1)));     \
      zqw[o+15]=l0|(l1<<16);                                                  \
    }                                                                         \
  }
  STAGE_ZR

  const int gtid = bx * 256 + tid;
  float4* f4 = (float4*)(out + OFF_OH + 3);
  const float4 zf4 = make_float4(0.f, 0.f, 0.f, 0.f);
  int sIdx = 0;
  int bi = 0;

  for (int dep = 0; dep < 3; ++dep) {
    asm volatile("s_waitcnt lgkmcnt(0)" ::: "memory");
    // B-fragments: z-tile st, scan col = c16, k-chunk = q  (16 B each)
    u32x4 B0 = *(const u32x4*)(zqw + ((0 * 16 + c16) * 16 + q * 4));
    u32x4 B1 = *(const u32x4*)(zqw + ((1 * 16 + c16) * 16 + q * 4));
    u32x4 B2 = *(const u32x4*)(zqw + ((2 * 16 + c16) * 16 + q * 4));
    u32x4 B3 = *(const u32x4*)(zqw + ((3 * 16 + c16) * 16 + q * 4));
    bshort8 b0 = __builtin_bit_cast(bshort8, B0);
    bshort8 b1 = __builtin_bit_cast(bshort8, B1);
    bshort8 b2 = __builtin_bit_cast(bshort8, B2);
    bshort8 b3 = __builtin_bit_cast(bshort8, B3);

    float m1_0 = 3.0e38f, m1_1 = 3.0e38f, m1_2 = 3.0e38f, m1_3 = 3.0e38f;
    float m2_0 = 3.0e38f, m2_1 = 3.0e38f, m2_2 = 3.0e38f, m2_3 = 3.0e38f;
    int   k1_0 = 0, k1_1 = 0, k1_2 = 0, k1_3 = 0;
    const int qc4 = q * 4;

    for (int ct = 0; ct < 64; ++ct) {
      f32x4 ehv = __builtin_bit_cast(f32x4, ((const float4*)ehs)[ct * 4 + q]);
      u32x4 A1u = wsn[ct * 64 + c16 * 4 + q];
      u32x4 A2u = wsn[ct * 64 + c16 * 4 + ((q + 2) & 3)];
      // interleaved onehot zero-fill: 2/ct in depth 0, 1/ct after (=256 total)
      if (dep == 0) {
        int sl = sIdx * 131072 + gtid; ++sIdx;
        if (sl < F4N) f4[sl] = zf4;
      }
      {
        int sl = sIdx * 131072 + gtid; ++sIdx;
        if (sl < F4N) f4[sl] = zf4;
      }
      bshort8 a1 = __builtin_bit_cast(bshort8, A1u);
      bshort8 a2 = __builtin_bit_cast(bshort8, A2u);
      const int cbase = ct * 16 + qc4;
#define UPD(V, CODE, M1, K1, M2)                                              \
      { float v_ = (V);                                                       \
        M2 = __builtin_amdgcn_fmed3f(v_, M1, M2);                             \
        bool lt_ = v_ < M1; M1 = lt_ ? v_ : M1; K1 = lt_ ? (CODE) : K1; }
#define DOST(BV, M1, K1, M2)                                                  \
      { f32x4 d1 = __builtin_amdgcn_mfma_f32_16x16x32_bf16(a1, BV, ehv, 0,0,0);\
        f32x4 dd = __builtin_amdgcn_mfma_f32_16x16x32_bf16(a2, BV, d1, 0,0,0);\
        UPD(dd.x, cbase + 0, M1, K1, M2)                                      \
        UPD(dd.y, cbase + 1, M1, K1, M2)                                      \
        UPD(dd.z, cbase + 2, M1, K1, M2)                                      \
        UPD(dd.w, cbase + 3, M1, K1, M2) }
      DOST(b0, m1_0, k1_0, m2_0)
      DOST(b1, m1_1, k1_1, m2_1)
      DOST(b2, m1_2, k1_2, m2_2)
      DOST(b3, m1_3, k1_3, m2_3)
#undef DOST
#undef UPD
    }
    // cross-quad reduce per scan-tile: lanes {s,s+16,s+32,s+48} share a scan
#define MERGE3(M1, K1, M2, OFF)                                               \
    { float om = __shfl_xor(M1, OFF); int ok = __shfl_xor(K1, OFF);           \
      float os = __shfl_xor(M2, OFF);                                         \
      float hi = fmaxf(M1, om);                                               \
      M2 = fminf(fminf(M2, os), hi);                                          \
      bool bw = (om < M1) || (om == M1 && ok < K1);                           \
      M1 = bw ? om : M1; K1 = bw ? ok : K1; }
    MERGE3(m1_0, k1_0, m2_0, 16) MERGE3(m1_0, k1_0, m2_0, 32)
    MERGE3(m1_1, k1_1, m2_1, 16) MERGE3(m1_1, k1_1, m2_1, 32)
    MERGE3(m1_2, k1_2, m2_2, 16) MERGE3(m1_2, k1_2, m2_2, 32)
    MERGE3(m1_3, k1_3, m2_3, 16) MERGE3(m1_3, k1_3, m2_3, 32)
#undef MERGE3
    // lane l owns scan l = (l>>4)*16 + (l&15): select tile (q) state
    float mA = (q & 1) ? m1_1 : m1_0,  mB = (q & 1) ? m1_3 : m1_2;
    float sA = (q & 1) ? m2_1 : m2_0,  sB = (q & 1) ? m2_3 : m2_2;
    int   kA = (q & 1) ? k1_1 : k1_0;  int kB = (q & 1) ? k1_3 : k1_2;
    float m1F = (q & 2) ? mB : mA;
    float m2F = (q & 2) ? sB : sA;
    int   k1F = (q & 2) ? kB : kA;

    bool fb = (__fsub_rn(m2F, m1F) < WEPS);
    unsigned long long mask = __ballot(fb);
    while (mask) {
      int ss = __ffsll((unsigned long long)mask) - 1;
      mask &= (mask - 1);
      Zr zs = load_zr(zbw + ss * 16);          // broadcast read
      float zsq = np_sumsq(zs);
      float db = 3.0e38f; int kb = 0;
      for (int i = 0; i < 16; ++i) {
        int kk = i * 64 + lane;
        Row rw = load_row(embn + kk * 16);
        float d = ref_d(zs, rw, zsq, esq[kk]);
        if (d < db) { db = d; kb = kk; }       // strict < => first within lane
      }
#pragma unroll
      for (int off = 1; off < 64; off <<= 1) { // lexicographic (d,k) min
        float od = __shfl_xor(db, off); int ok = __shfl_xor(kb, off);
        if (od < db || (od == db && ok < kb)) { db = od; kb = ok; }
      }
      if (lane == ss) k1F = kb;
    }
    bi = k1F;
    // residual update (fp32, ref-exact elementwise chain)
    zr = sub_row(zr, load_row(embn + k1F * 16));
    if (dep < 2) { STAGE_ZR }
  }
  for (; sIdx < 256; ++sIdx) {                 // safety flush (normally none)
    int sl = sIdx * 131072 + gtid;
    if (sl < F4N) f4[sl] = zf4;
  }
  // idx + mean(q) = (z_orig - zr_final)/3  (R5/R6-verified path)
  out[OFF_IDX + scanB * NSUB + n] = (float)bi;
  {
    Zr zo = load_zr(z + scanB * DIMD + n * ED);
    float* mp2 = out + OFF_ZQ + scanB * DIMD + n * ED;
    mp2[0]  = __fdiv_rn(__fsub_rn(zo.p0.x, zr.p0.x), 3.0f);
    mp2[1]  = __fdiv_rn(__fsub_rn(zo.p0.y, zr.p0.y), 3.0f);
    mp2[2]  = __fdiv_rn(__fsub_rn(zo.p1.x, zr.p1.x), 3.0f);
    mp2[3]  = __fdiv_rn(__fsub_rn(zo.p1.y, zr.p1.y), 3.0f);
    mp2[4]  = __fdiv_rn(__fsub_rn(zo.p2.x, zr.p2.x), 3.0f);
    mp2[5]  = __fdiv_rn(__fsub_rn(zo.p2.y, zr.p2.y), 3.0f);
    mp2[6]  = __fdiv_rn(__fsub_rn(zo.p3.x, zr.p3.x), 3.0f);
    mp2[7]  = __fdiv_rn(__fsub_rn(zo.p3.y, zr.p3.y), 3.0f);
    mp2[8]  = __fdiv_rn(__fsub_rn(zo.p4.x, zr.p4.x), 3.0f);
    mp2[9]  = __fdiv_rn(__fsub_rn(zo.p4.y, zr.p4.y), 3.0f);
    mp2[10] = __fdiv_rn(__fsub_rn(zo.p5.x, zr.p5.x), 3.0f);
    mp2[11] = __fdiv_rn(__fsub_rn(zo.p5.y, zr.p5.y), 3.0f);
    mp2[12] = __fdiv_rn(__fsub_rn(zo.p6.x, zr.p6.x), 3.0f);
    mp2[13] = __fdiv_rn(__fsub_rn(zo.p6.y, zr.p6.y), 3.0f);
    mp2[14] = __fdiv_rn(__fsub_rn(zo.p7.x, zr.p7.x), 3.0f);
    mp2[15] = __fdiv_rn(__fsub_rn(zo.p7.y, zr.p7.y), 3.0f);
  }
#undef STAGE_ZR
}

// ---------------------------------------------------------------------------
// Kernel 2: scatter the ones into the (already zeroed) onehot region.
// ---------------------------------------------------------------------------
__global__ void vq_ones(float* __restrict__ out) {
  int g = blockIdx.x * 256 + threadIdx.x;          // 0 .. 131071 == b*16+n
  int k = (int)out[OFF_IDX + g];
  out[OFF_OH + g * KC + k] = 1.0f;
}

// ---------------------------------------------------------------------------
// Kernel 3: z_q = mean @ W + b, straight-through output, loss.
// ---------------------------------------------------------------------------
#define TB 16
__global__ __launch_bounds__(256, 2) void vq_head(
    const float* __restrict__ z, const float* __restrict__ W,
    const float* __restrict__ bias, float* __restrict__ out) {
  __shared__ float ml[TB][DIMD];   // 16KB
  __shared__ double reds[4];
  const int t  = threadIdx.x;
  const int r0 = blockIdx.x * TB;
  for (int j = t; j < TB * DIMD; j += 256) {
    int r = j >> 8, d = j & 255;
    ml[r][d] = out[OFF_ZQ + (r0 + r) * DIMD + d];
  }
  __syncthreads();
  float acc[TB];
#pragma unroll
  for (int r = 0; r < TB; ++r) acc[r] = 0.f;
  for (int d = 0; d < DIMD; ++d) {
    float w = W[d * DIMD + t];
#pragma unroll
    for (int r = 0; r < TB; ++r) acc[r] = fmaf(ml[r][d], w, acc[r]);
  }
  const float bv = bias[t];
  double lp = 0.0;
#pragma unroll
  for (int r = 0; r < TB; ++r) {
    float zq   = acc[r] + bv;
    float zv   = z[(r0 + r) * DIMD + t];
    float diff = zq - zv;
    out[OFF_ZQ + (r0 + r) * DIMD + t] = zv + diff;
    lp += (double)diff * (double)diff;
  }
#pragma unroll
  for (int o = 32; o > 0; o >>= 1) lp += __shfl_down(lp, o);
  if ((t & 63) == 0) reds[t >> 6] = lp;
  __syncthreads();
  if (t == 0) {
    double tot = reds[0] + reds[1] + reds[2] + reds[3];
    atomicAdd(out, (float)(tot * (1.25 / (double)(BQ * DIMD))));
  }
}

extern "C" void kernel_launch(void* const* d_in, const int* in_sizes, int n_in,
                              void* d_out, int out_size, void* d_ws, size_t ws_size,
                              hipStream_t stream) {
  const float* z    = (const float*)d_in[0];
  const float* emb  = (const float*)d_in[1];
  const float* W    = (const float*)d_in[2];
  const float* bias = (const float*)d_in[3];
  float* out = (float*)d_out;
  unsigned int* wsp = (unsigned int*)d_ws;       // 1 MB split codebook
  vq_prep<<<dim3(64), dim3(256), 0, stream>>>(emb, wsp);
  vq_main<<<dim3((BQ / 256) * NSUB), dim3(256), 0, stream>>>(z, emb, wsp, out);
  vq_ones<<<dim3((BQ * NSUB) / 256), dim3(256), 0, stream>>>(out);
  vq_head<<<dim3(BQ / TB), dim3(256), 0, stream>>>(z, W, bias, out);
}

// Round 9
// 688.347 us; speedup vs baseline: 1.5975x; 1.0301x over previous
//
#include <hip/hip_runtime.h>
#include <math.h>

#define BQ    8192
#define DIMD  256
#define NSUB  16
#define KC    1024
#define ED    16
#define SCW   32                            // scans per wave (2 C-tiles)

#define OFF_ZQ   1
#define OFF_OH   (1 + BQ * DIMD)            // 2097153
#define OH_ELEMS (BQ * NSUB * KC)           // 134217728
#define OFF_IDX  (OFF_OH + OH_ELEMS)        // 136314881
#define F4N      ((OH_ELEMS - 4) / 4)       // 33554431 aligned float4 slots
#define NTHR     (1024 * 256)               // vq_main total threads
#define WEPS     2e-4f                      // ambiguity window (v-units)

typedef __attribute__((ext_vector_type(2))) float v2f;
typedef __attribute__((ext_vector_type(4))) float f32x4;
typedef __attribute__((ext_vector_type(8))) short bshort8;
typedef __attribute__((ext_vector_type(4))) unsigned int u32x4;

struct Zr  { v2f p0, p1, p2, p3, p4, p5, p6, p7; };   // one residual (16 f)
struct Row { float4 c0, c1, c2, c3; };                 // one codebook row
struct V2x2 { v2f lo, hi; };

// numpy pairwise sum-of-squares (verified R3).
__device__ __forceinline__ float np_sumsq(Zr z) {
  float q0 = __fmul_rn(z.p0.x, z.p0.x), q1 = __fmul_rn(z.p0.y, z.p0.y);
  float q2 = __fmul_rn(z.p1.x, z.p1.x), q3 = __fmul_rn(z.p1.y, z.p1.y);
  float q4 = __fmul_rn(z.p2.x, z.p2.x), q5 = __fmul_rn(z.p2.y, z.p2.y);
  float q6 = __fmul_rn(z.p3.x, z.p3.x), q7 = __fmul_rn(z.p3.y, z.p3.y);
  float q8 = __fmul_rn(z.p4.x, z.p4.x), q9 = __fmul_rn(z.p4.y, z.p4.y);
  float qa = __fmul_rn(z.p5.x, z.p5.x), qb = __fmul_rn(z.p5.y, z.p5.y);
  float qc = __fmul_rn(z.p6.x, z.p6.x), qd = __fmul_rn(z.p6.y, z.p6.y);
  float qe = __fmul_rn(z.p7.x, z.p7.x), qf = __fmul_rn(z.p7.y, z.p7.y);
  float r0 = __fadd_rn(q0, q8), r1 = __fadd_rn(q1, q9);
  float r2 = __fadd_rn(q2, qa), r3 = __fadd_rn(q3, qb);
  float r4 = __fadd_rn(q4, qc), r5 = __fadd_rn(q5, qd);
  float r6 = __fadd_rn(q6, qe), r7 = __fadd_rn(q7, qf);
  return __fadd_rn(__fadd_rn(__fadd_rn(r0, r1), __fadd_rn(r2, r3)),
                   __fadd_rn(__fadd_rn(r4, r5), __fadd_rn(r6, r7)));
}

// Reference-rounded distance (verified R3): SSE-lane einsum SOP + hadd,
// step-rounded d^2 assembly, fp64 sqrt (correctly rounded, CPU-bit-exact).
__device__ __forceinline__ float ref_d(Zr z, Row rw, float zsq, float esq) {
  float p0  = __fmul_rn(z.p0.x, rw.c0.x), p1  = __fmul_rn(z.p0.y, rw.c0.y);
  float p2  = __fmul_rn(z.p1.x, rw.c0.z), p3  = __fmul_rn(z.p1.y, rw.c0.w);
  float p4  = __fmul_rn(z.p2.x, rw.c1.x), p5  = __fmul_rn(z.p2.y, rw.c1.y);
  float p6  = __fmul_rn(z.p3.x, rw.c1.z), p7  = __fmul_rn(z.p3.y, rw.c1.w);
  float p8  = __fmul_rn(z.p4.x, rw.c2.x), p9  = __fmul_rn(z.p4.y, rw.c2.y);
  float p10 = __fmul_rn(z.p5.x, rw.c2.z), p11 = __fmul_rn(z.p5.y, rw.c2.w);
  float p12 = __fmul_rn(z.p6.x, rw.c3.x), p13 = __fmul_rn(z.p6.y, rw.c3.y);
  float p14 = __fmul_rn(z.p7.x, rw.c3.z), p15 = __fmul_rn(z.p7.y, rw.c3.w);
  float L0 = __fadd_rn(__fadd_rn(__fadd_rn(p0, p4), p8),  p12);
  float L1 = __fadd_rn(__fadd_rn(__fadd_rn(p1, p5), p9),  p13);
  float L2 = __fadd_rn(__fadd_rn(__fadd_rn(p2, p6), p10), p14);
  float L3 = __fadd_rn(__fadd_rn(__fadd_rn(p3, p7), p11), p15);
  float cross = __fadd_rn(__fadd_rn(L0, L1), __fadd_rn(L2, L3));
  float t = __fsub_rn(zsq, __fmul_rn(2.0f, cross));
  t = __fadd_rn(t, esq);
  t = fmaxf(t, 0.0f);
  return (float)sqrt((double)t);
}

__device__ __forceinline__ Zr sub_row(Zr z, Row rw) {   // elementwise __fsub_rn
  Zr o;
  o.p0 = (v2f){__fsub_rn(z.p0.x, rw.c0.x), __fsub_rn(z.p0.y, rw.c0.y)};
  o.p1 = (v2f){__fsub_rn(z.p1.x, rw.c0.z), __fsub_rn(z.p1.y, rw.c0.w)};
  o.p2 = (v2f){__fsub_rn(z.p2.x, rw.c1.x), __fsub_rn(z.p2.y, rw.c1.y)};
  o.p3 = (v2f){__fsub_rn(z.p3.x, rw.c1.z), __fsub_rn(z.p3.y, rw.c1.w)};
  o.p4 = (v2f){__fsub_rn(z.p4.x, rw.c2.x), __fsub_rn(z.p4.y, rw.c2.y)};
  o.p5 = (v2f){__fsub_rn(z.p5.x, rw.c2.z), __fsub_rn(z.p5.y, rw.c2.w)};
  o.p6 = (v2f){__fsub_rn(z.p6.x, rw.c3.x), __fsub_rn(z.p6.y, rw.c3.y)};
  o.p7 = (v2f){__fsub_rn(z.p7.x, rw.c3.z), __fsub_rn(z.p7.y, rw.c3.w)};
  return o;
}

__device__ __forceinline__ Zr load_zr(const float* p) {
  const float4* zp = (const float4*)p;
  float4 a0 = zp[0], a1 = zp[1], a2 = zp[2], a3 = zp[3];
  V2x2 v0 = __builtin_bit_cast(V2x2, a0), v1 = __builtin_bit_cast(V2x2, a1);
  V2x2 v2 = __builtin_bit_cast(V2x2, a2), v3 = __builtin_bit_cast(V2x2, a3);
  Zr z;
  z.p0 = v0.lo; z.p1 = v0.hi; z.p2 = v1.lo; z.p3 = v1.hi;
  z.p4 = v2.lo; z.p5 = v2.hi; z.p6 = v3.lo; z.p7 = v3.hi;
  return z;
}

__device__ __forceinline__ Row load_row(const float* p) {
  const float4* cp = (const float4*)p;
  Row rw; rw.c0 = cp[0]; rw.c1 = cp[1]; rw.c2 = cp[2]; rw.c3 = cp[3];
  return rw;
}

// fp32 -> bf16 (RNE) and back; fast-path only (window absorbs any mode diff).
__device__ __forceinline__ unsigned int f2bf(float x) {
  unsigned int u = __float_as_uint(x);
  return (u + 0x7FFFu + ((u >> 16) & 1u)) >> 16;
}
__device__ __forceinline__ float bf2f(unsigned int b) {
  return __uint_as_float(b << 16);
}

// stage one residual: fp32 copy + bf16 hi/lo split (identical math to R7)
__device__ __forceinline__ void stage_zr(Zr zr, unsigned int* zqp, float* zbp) {
  v2f* zb2 = (v2f*)zbp;
  zb2[0]=zr.p0; zb2[1]=zr.p1; zb2[2]=zr.p2; zb2[3]=zr.p3;
  zb2[4]=zr.p4; zb2[5]=zr.p5; zb2[6]=zr.p6; zb2[7]=zr.p7;
  v2f P; unsigned h0, h1, l0, l1;
#define PK(I, PP)                                                             \
  P = PP; h0 = f2bf(P.x); h1 = f2bf(P.y); zqp[I] = h0 | (h1 << 16);           \
  l0 = f2bf(__fsub_rn(P.x, bf2f(h0))); l1 = f2bf(__fsub_rn(P.y, bf2f(h1)));   \
  zqp[8 + I] = l0 | (l1 << 16);
  PK(0, zr.p0) PK(1, zr.p1) PK(2, zr.p2) PK(3, zr.p3)
  PK(4, zr.p4) PK(5, zr.p5) PK(6, zr.p6) PK(7, zr.p7)
#undef PK
}

// ---------------------------------------------------------------------------
// Prep: split-negate codebook into ws A-frag region + esq table.
// Row 64B = [bf16 hi(-c) x16 | bf16 lo(-c) x16]; esq[row] = np_sumsq(c).
// ---------------------------------------------------------------------------
__global__ void vq_prep(const float* __restrict__ emb,
                        unsigned int* __restrict__ ws) {
  const int row = blockIdx.x * 256 + threadIdx.x;   // 16384 rows (n*1024+k)
  const float* c = emb + row * 16;
  unsigned int o[16];
#pragma unroll
  for (int u = 0; u < 8; ++u) {
    float a = -c[2 * u], b = -c[2 * u + 1];
    unsigned int h0 = f2bf(a), h1 = f2bf(b);
    o[u] = h0 | (h1 << 16);
    unsigned int l0 = f2bf(__fsub_rn(a, bf2f(h0)));
    unsigned int l1 = f2bf(__fsub_rn(b, bf2f(h1)));
    o[8 + u] = l0 | (l1 << 16);
  }
  u32x4* dst = (u32x4*)ws + row * 4;
#pragma unroll
  for (int j = 0; j < 4; ++j)
    dst[j] = (u32x4){o[4 * j], o[4 * j + 1], o[4 * j + 2], o[4 * j + 3]};
  // esq (np_sumsq of +c; squares of -c identical bit-exact)
  float* esqg = (float*)(ws + 16384 * 16);
  esqg[row] = np_sumsq(load_zr(c));
}

// ---------------------------------------------------------------------------
// Kernel 1: MFMA scan. Block = 128 scans x 1 n (4 waves x 32 scans); wave =
// 2 C-tiles x full k. Prefetched A-frags; (m1,k1,m2) gap test; rare exact
// ref_d fallback. Onehot zero-fill interleaved, nontemporal, all 3 depths.
// ---------------------------------------------------------------------------
__global__ __launch_bounds__(256, 4) void vq_main(
    const float* __restrict__ z, const float* __restrict__ emb,
    const unsigned int* __restrict__ ws, float* __restrict__ out) {
  __shared__ float esq[KC];                    // 4 KB
  __shared__ float ehs[KC];                    // 4 KB
  __shared__ unsigned int zq[4 * SCW * 16];    // 8 KB bf16-split residuals
  __shared__ float zb[4 * SCW * 16];           // 8 KB fp32 residuals (24 KB)
  const int tid   = threadIdx.x;
  const int bx    = blockIdx.x;
  const int n     = bx & 15;
  const int bbase = (bx >> 4) * 128;
  const int w     = tid >> 6;
  const int lane  = tid & 63;
  const int q     = lane >> 4;
  const int c16   = lane & 15;
  const int sc    = lane & 31;                 // scan within wave (twin lanes)
  const float* embn = emb + n * (KC * ED);
  const u32x4* wsn  = (const u32x4*)ws + n * (KC * 4);
  const float* esqg = (const float*)(ws + 16384 * 16) + n * KC;

  for (int k = tid; k < KC; k += 256) {
    float s = esqg[k];
    esq[k] = s; ehs[k] = 0.5f * s;
  }
  if (bx == 0 && tid == 0) {
    out[0] = 0.f;
    out[OFF_OH + 0] = 0.f; out[OFF_OH + 1] = 0.f; out[OFF_OH + 2] = 0.f;
    out[OFF_OH + OH_ELEMS - 1] = 0.f;
  }
  __syncthreads();

  const int scanB = bbase + w * SCW + sc;
  Zr zr = load_zr(z + scanB * DIMD + n * ED);
  unsigned int* zqw = zq + w * (SCW * 16);
  float*        zbw = zb + w * (SCW * 16);
  if (lane < SCW) stage_zr(zr, zqw + sc * 16, zbw + sc * 16);

  const int gtid = bx * 256 + tid;             // 0 .. NTHR-1
  f32x4* f4 = (f32x4*)(out + OFF_OH + 3);      // 16B-aligned, ext-vector type
  const f32x4 zf4 = {0.f, 0.f, 0.f, 0.f};
  int sIdx = 0, fcnt = 0;
  int bi = 0;

  for (int dep = 0; dep < 3; ++dep) {
    asm volatile("s_waitcnt lgkmcnt(0)" ::: "memory");
    u32x4 B0u = *(const u32x4*)(zqw + ((0 * 16 + c16) * 16 + q * 4));
    u32x4 B1u = *(const u32x4*)(zqw + ((1 * 16 + c16) * 16 + q * 4));
    bshort8 b0 = __builtin_bit_cast(bshort8, B0u);
    bshort8 b1 = __builtin_bit_cast(bshort8, B1u);

    float m1_0 = 3.0e38f, m1_1 = 3.0e38f;
    float m2_0 = 3.0e38f, m2_1 = 3.0e38f;
    int   k1_0 = 0, k1_1 = 0;
    const int qc4 = q * 4;
    const int aoff = c16 * 4 + q, boff = c16 * 4 + ((q + 2) & 3);

    // prefetch ct=0
    u32x4 A1n = wsn[aoff], A2n = wsn[boff];
    float4 ehn = ((const float4*)ehs)[q];

    for (int ct = 0; ct < 64; ++ct) {
      u32x4 A1c = A1n, A2c = A2n;
      f32x4 ehv = __builtin_bit_cast(f32x4, ehn);
      if (ct < 63) {
        const int nb = (ct + 1) * 64;
        A1n = wsn[nb + aoff];
        A2n = wsn[nb + boff];
        ehn = ((const float4*)ehs)[(ct + 1) * 4 + q];
      }
      if (fcnt != 2) {                          // 2 fill stores per 3 cts
        int sl = sIdx * NTHR + gtid; ++sIdx;
        if (sl < F4N) __builtin_nontemporal_store(zf4, f4 + sl);
      }
      fcnt = (fcnt == 2) ? 0 : fcnt + 1;
      bshort8 a1 = __builtin_bit_cast(bshort8, A1c);
      bshort8 a2 = __builtin_bit_cast(bshort8, A2c);
      const int cbase = ct * 16 + qc4;
#define UPD(V, CODE, M1, K1, M2)                                              \
      { float v_ = (V);                                                       \
        M2 = __builtin_amdgcn_fmed3f(v_, M1, M2);                             \
        bool lt_ = v_ < M1; M1 = lt_ ? v_ : M1; K1 = lt_ ? (CODE) : K1; }
#define DOST(BV, M1, K1, M2)                                                  \
      { f32x4 d1 = __builtin_amdgcn_mfma_f32_16x16x32_bf16(a1, BV, ehv, 0,0,0);\
        f32x4 dd = __builtin_amdgcn_mfma_f32_16x16x32_bf16(a2, BV, d1, 0,0,0);\
        UPD(dd.x, cbase + 0, M1, K1, M2)                                      \
        UPD(dd.y, cbase + 1, M1, K1, M2)                                      \
        UPD(dd.z, cbase + 2, M1, K1, M2)                                      \
        UPD(dd.w, cbase + 3, M1, K1, M2) }
      DOST(b0, m1_0, k1_0, m2_0)
      DOST(b1, m1_1, k1_1, m2_1)
#undef DOST
#undef UPD
    }
    // cross-quad reduce: lanes {s, s^16, s^32, s^48} share a scan per tile
#define MERGE3(M1, K1, M2, OFF)                                               \
    { float om = __shfl_xor(M1, OFF); int ok = __shfl_xor(K1, OFF);           \
      float os = __shfl_xor(M2, OFF);                                         \
      float hi = fmaxf(M1, om);                                               \
      M2 = fminf(fminf(M2, os), hi);                                          \
      bool bw = (om < M1) || (om == M1 && ok < K1);                           \
      M1 = bw ? om : M1; K1 = bw ? ok : K1; }
    MERGE3(m1_0, k1_0, m2_0, 16) MERGE3(m1_0, k1_0, m2_0, 32)
    MERGE3(m1_1, k1_1, m2_1, 16) MERGE3(m1_1, k1_1, m2_1, 32)
#undef MERGE3
    // lane (l&31) owns scan l&31; tile = (l&31)>=16
    const bool t1 = (sc >= 16);
    float m1F = t1 ? m1_1 : m1_0;
    float m2F = t1 ? m2_1 : m2_0;
    int   k1F = t1 ? k1_1 : k1_0;

    bool fb = (lane < SCW) && (__fsub_rn(m2F, m1F) < WEPS);
    unsigned long long mask = __ballot(fb);
    while (mask) {
      int ss = __ffsll((unsigned long long)mask) - 1;
      mask &= (mask - 1);
      Zr zs = load_zr(zbw + ss * 16);          // broadcast read
      float zsq = np_sumsq(zs);
      float db = 3.0e38f; int kb = 0;
      for (int i = 0; i < 16; ++i) {
        int kk = i * 64 + lane;
        Row rw = load_row(embn + kk * 16);
        float d = ref_d(zs, rw, zsq, esq[kk]);
        if (d < db) { db = d; kb = kk; }       // strict < => first within lane
      }
#pragma unroll
      for (int off = 1; off < 64; off <<= 1) { // lexicographic (d,k) min
        float od = __shfl_xor(db, off); int ok = __shfl_xor(kb, off);
        if (od < db || (od == db && ok < kb)) { db = od; kb = ok; }
      }
      if (lane == ss) k1F = kb;
    }
    k1F = __shfl(k1F, sc);                     // twin-broadcast (lanes >= 32)
    bi = k1F;
    // residual update (fp32, ref-exact elementwise chain)
    zr = sub_row(zr, load_row(embn + k1F * 16));
    if (dep < 2 && lane < SCW) stage_zr(zr, zqw + sc * 16, zbw + sc * 16);
  }
  for (; sIdx < 128; ++sIdx) {                 // safety flush (normally none)
    int sl = sIdx * NTHR + gtid;
    if (sl < F4N) __builtin_nontemporal_store(zf4, f4 + sl);
  }
  // lanes < 32 write idx + mean(q) = (z_orig - zr_final)/3 (verified path)
  if (lane < SCW) {
    out[OFF_IDX + scanB * NSUB + n] = (float)bi;
    Zr zo = load_zr(z + scanB * DIMD + n * ED);
    float* mp2 = out + OFF_ZQ + scanB * DIMD + n * ED;
    mp2[0]  = __fdiv_rn(__fsub_rn(zo.p0.x, zr.p0.x), 3.0f);
    mp2[1]  = __fdiv_rn(__fsub_rn(zo.p0.y, zr.p0.y), 3.0f);
    mp2[2]  = __fdiv_rn(__fsub_rn(zo.p1.x, zr.p1.x), 3.0f);
    mp2[3]  = __fdiv_rn(__fsub_rn(zo.p1.y, zr.p1.y), 3.0f);
    mp2[4]  = __fdiv_rn(__fsub_rn(zo.p2.x, zr.p2.x), 3.0f);
    mp2[5]  = __fdiv_rn(__fsub_rn(zo.p2.y, zr.p2.y), 3.0f);
    mp2[6]  = __fdiv_rn(__fsub_rn(zo.p3.x, zr.p3.x), 3.0f);
    mp2[7]  = __fdiv_rn(__fsub_rn(zo.p3.y, zr.p3.y), 3.0f);
    mp2[8]  = __fdiv_rn(__fsub_rn(zo.p4.x, zr.p4.x), 3.0f);
    mp2[9]  = __fdiv_rn(__fsub_rn(zo.p4.y, zr.p4.y), 3.0f);
    mp2[10] = __fdiv_rn(__fsub_rn(zo.p5.x, zr.p5.x), 3.0f);
    mp2[11] = __fdiv_rn(__fsub_rn(zo.p5.y, zr.p5.y), 3.0f);
    mp2[12] = __fdiv_rn(__fsub_rn(zo.p6.x, zr.p6.x), 3.0f);
    mp2[13] = __fdiv_rn(__fsub_rn(zo.p6.y, zr.p6.y), 3.0f);
    mp2[14] = __fdiv_rn(__fsub_rn(zo.p7.x, zr.p7.x), 3.0f);
    mp2[15] = __fdiv_rn(__fsub_rn(zo.p7.y, zr.p7.y), 3.0f);
  }
}

// ---------------------------------------------------------------------------
// Kernel 2: scatter the ones into the (already zeroed) onehot region.
// ---------------------------------------------------------------------------
__global__ void vq_ones(float* __restrict__ out) {
  int g = blockIdx.x * 256 + threadIdx.x;          // 0 .. 131071 == b*16+n
  int k = (int)out[OFF_IDX + g];
  out[OFF_OH + g * KC + k] = 1.0f;
}

// ---------------------------------------------------------------------------
// Kernel 3: z_q = mean @ W + b, straight-through output, loss.
// ---------------------------------------------------------------------------
#define TB 16
__global__ __launch_bounds__(256, 2) void vq_head(
    const float* __restrict__ z, const float* __restrict__ W,
    const float* __restrict__ bias, float* __restrict__ out) {
  __shared__ float ml[TB][DIMD];   // 16KB
  __shared__ double reds[4];
  const int t  = threadIdx.x;
  const int r0 = blockIdx.x * TB;
  for (int j = t; j < TB * DIMD; j += 256) {
    int r = j >> 8, d = j & 255;
    ml[r][d] = out[OFF_ZQ + (r0 + r) * DIMD + d];
  }
  __syncthreads();
  float acc[TB];
#pragma unroll
  for (int r = 0; r < TB; ++r) acc[r] = 0.f;
  for (int d = 0; d < DIMD; ++d) {
    float w = W[d * DIMD + t];
#pragma unroll
    for (int r = 0; r < TB; ++r) acc[r] = fmaf(ml[r][d], w, acc[r]);
  }
  const float bv = bias[t];
  double lp = 0.0;
#pragma unroll
  for (int r = 0; r < TB; ++r) {
    float zq   = acc[r] + bv;
    float zv   = z[(r0 + r) * DIMD + t];
    float diff = zq - zv;
    out[OFF_ZQ + (r0 + r) * DIMD + t] = zv + diff;
    lp += (double)diff * (double)diff;
  }
#pragma unroll
  for (int o = 32; o > 0; o >>= 1) lp += __shfl_down(lp, o);
  if ((t & 63) == 0) reds[t >> 6] = lp;
  __syncthreads();
  if (t == 0) {
    double tot = reds[0] + reds[1] + reds[2] + reds[3];
    atomicAdd(out, (float)(tot * (1.25 / (double)(BQ * DIMD))));
  }
}

extern "C" void kernel_launch(void* const* d_in, const int* in_sizes, int n_in,
                              void* d_out, int out_size, void* d_ws, size_t ws_size,
                              hipStream_t stream) {
  const float* z    = (const float*)d_in[0];
  const float* emb  = (const float*)d_in[1];
  const float* W    = (const float*)d_in[2];
  const float* bias = (const float*)d_in[3];
  float* out = (float*)d_out;
  unsigned int* wsp = (unsigned int*)d_ws;       // 1 MB A-frags + 64 KB esq
  vq_prep<<<dim3(64), dim3(256), 0, stream>>>(emb, wsp);
  vq_main<<<dim3((BQ / 128) * NSUB), dim3(256), 0, stream>>>(z, emb, wsp, out);
  vq_ones<<<dim3((BQ * NSUB) / 256), dim3(256), 0, stream>>>(out);
  vq_head<<<dim3(BQ / TB), dim3(256), 0, stream>>>(z, W, bias, out);
}

// Round 10
// 679.267 us; speedup vs baseline: 1.6189x; 1.0134x over previous
//
#include <hip/hip_runtime.h>
#include <math.h>

#define BQ    8192
#define DIMD  256
#define NSUB  16
#define KC    1024
#define ED    16
#define SCW   32                            // scans per wave (2 C-tiles)

#define OFF_ZQ   1
#define OFF_OH   (1 + BQ * DIMD)            // 2097153
#define OH_ELEMS (BQ * NSUB * KC)           // 134217728
#define OFF_IDX  (OFF_OH + OH_ELEMS)        // 136314881
#define F4N      ((OH_ELEMS - 4) / 4)       // 33554431 aligned float4 slots
#define NTHR     (1024 * 256)               // vq_main total threads

typedef __attribute__((ext_vector_type(2))) float v2f;
typedef __attribute__((ext_vector_type(4))) float f32x4;
typedef __attribute__((ext_vector_type(8))) short bshort8;
typedef __attribute__((ext_vector_type(4))) unsigned int u32x4;

struct Zr  { v2f p0, p1, p2, p3, p4, p5, p6, p7; };   // one residual (16 f)
struct Row { float4 c0, c1, c2, c3; };                 // one codebook row
struct V2x2 { v2f lo, hi; };

// numpy pairwise sum-of-squares (verified R3).
__device__ __forceinline__ float np_sumsq(Zr z) {
  float q0 = __fmul_rn(z.p0.x, z.p0.x), q1 = __fmul_rn(z.p0.y, z.p0.y);
  float q2 = __fmul_rn(z.p1.x, z.p1.x), q3 = __fmul_rn(z.p1.y, z.p1.y);
  float q4 = __fmul_rn(z.p2.x, z.p2.x), q5 = __fmul_rn(z.p2.y, z.p2.y);
  float q6 = __fmul_rn(z.p3.x, z.p3.x), q7 = __fmul_rn(z.p3.y, z.p3.y);
  float q8 = __fmul_rn(z.p4.x, z.p4.x), q9 = __fmul_rn(z.p4.y, z.p4.y);
  float qa = __fmul_rn(z.p5.x, z.p5.x), qb = __fmul_rn(z.p5.y, z.p5.y);
  float qc = __fmul_rn(z.p6.x, z.p6.x), qd = __fmul_rn(z.p6.y, z.p6.y);
  float qe = __fmul_rn(z.p7.x, z.p7.x), qf = __fmul_rn(z.p7.y, z.p7.y);
  float r0 = __fadd_rn(q0, q8), r1 = __fadd_rn(q1, q9);
  float r2 = __fadd_rn(q2, qa), r3 = __fadd_rn(q3, qb);
  float r4 = __fadd_rn(q4, qc), r5 = __fadd_rn(q5, qd);
  float r6 = __fadd_rn(q6, qe), r7 = __fadd_rn(q7, qf);
  return __fadd_rn(__fadd_rn(__fadd_rn(r0, r1), __fadd_rn(r2, r3)),
                   __fadd_rn(__fadd_rn(r4, r5), __fadd_rn(r6, r7)));
}

// Reference-rounded distance (verified R3): SSE-lane einsum SOP + hadd,
// step-rounded d^2 assembly, fp64 sqrt (correctly rounded, CPU-bit-exact).
__device__ __forceinline__ float ref_d(Zr z, Row rw, float zsq, float esq) {
  float p0  = __fmul_rn(z.p0.x, rw.c0.x), p1  = __fmul_rn(z.p0.y, rw.c0.y);
  float p2  = __fmul_rn(z.p1.x, rw.c0.z), p3  = __fmul_rn(z.p1.y, rw.c0.w);
  float p4  = __fmul_rn(z.p2.x, rw.c1.x), p5  = __fmul_rn(z.p2.y, rw.c1.y);
  float p6  = __fmul_rn(z.p3.x, rw.c1.z), p7  = __fmul_rn(z.p3.y, rw.c1.w);
  float p8  = __fmul_rn(z.p4.x, rw.c2.x), p9  = __fmul_rn(z.p4.y, rw.c2.y);
  float p10 = __fmul_rn(z.p5.x, rw.c2.z), p11 = __fmul_rn(z.p5.y, rw.c2.w);
  float p12 = __fmul_rn(z.p6.x, rw.c3.x), p13 = __fmul_rn(z.p6.y, rw.c3.y);
  float p14 = __fmul_rn(z.p7.x, rw.c3.z), p15 = __fmul_rn(z.p7.y, rw.c3.w);
  float L0 = __fadd_rn(__fadd_rn(__fadd_rn(p0, p4), p8),  p12);
  float L1 = __fadd_rn(__fadd_rn(__fadd_rn(p1, p5), p9),  p13);
  float L2 = __fadd_rn(__fadd_rn(__fadd_rn(p2, p6), p10), p14);
  float L3 = __fadd_rn(__fadd_rn(__fadd_rn(p3, p7), p11), p15);
  float cross = __fadd_rn(__fadd_rn(L0, L1), __fadd_rn(L2, L3));
  float t = __fsub_rn(zsq, __fmul_rn(2.0f, cross));
  t = __fadd_rn(t, esq);
  t = fmaxf(t, 0.0f);
  return (float)sqrt((double)t);
}

// scalar fast value (packed fp32 FMA) — fallback gate only (~3e-7 err)
__device__ __forceinline__ float fastv_s(Zr z, Row rw, float eh) {
  V2x2 a0 = __builtin_bit_cast(V2x2, rw.c0);
  V2x2 a1 = __builtin_bit_cast(V2x2, rw.c1);
  V2x2 a2 = __builtin_bit_cast(V2x2, rw.c2);
  V2x2 a3 = __builtin_bit_cast(V2x2, rw.c3);
  v2f accA = {eh, 0.f}, accB = {0.f, 0.f};
  accA = __builtin_elementwise_fma(-z.p0, a0.lo, accA);
  accB = __builtin_elementwise_fma(-z.p1, a0.hi, accB);
  accA = __builtin_elementwise_fma(-z.p2, a1.lo, accA);
  accB = __builtin_elementwise_fma(-z.p3, a1.hi, accB);
  accA = __builtin_elementwise_fma(-z.p4, a2.lo, accA);
  accB = __builtin_elementwise_fma(-z.p5, a2.hi, accB);
  accA = __builtin_elementwise_fma(-z.p6, a3.lo, accA);
  accB = __builtin_elementwise_fma(-z.p7, a3.hi, accB);
  v2f acc = accA + accB;
  return acc.x + acc.y;
}

__device__ __forceinline__ Zr sub_row(Zr z, Row rw) {   // elementwise __fsub_rn
  Zr o;
  o.p0 = (v2f){__fsub_rn(z.p0.x, rw.c0.x), __fsub_rn(z.p0.y, rw.c0.y)};
  o.p1 = (v2f){__fsub_rn(z.p1.x, rw.c0.z), __fsub_rn(z.p1.y, rw.c0.w)};
  o.p2 = (v2f){__fsub_rn(z.p2.x, rw.c1.x), __fsub_rn(z.p2.y, rw.c1.y)};
  o.p3 = (v2f){__fsub_rn(z.p3.x, rw.c1.z), __fsub_rn(z.p3.y, rw.c1.w)};
  o.p4 = (v2f){__fsub_rn(z.p4.x, rw.c2.x), __fsub_rn(z.p4.y, rw.c2.y)};
  o.p5 = (v2f){__fsub_rn(z.p5.x, rw.c2.z), __fsub_rn(z.p5.y, rw.c2.w)};
  o.p6 = (v2f){__fsub_rn(z.p6.x, rw.c3.x), __fsub_rn(z.p6.y, rw.c3.y)};
  o.p7 = (v2f){__fsub_rn(z.p7.x, rw.c3.z), __fsub_rn(z.p7.y, rw.c3.w)};
  return o;
}

__device__ __forceinline__ Zr load_zr(const float* p) {
  const float4* zp = (const float4*)p;
  float4 a0 = zp[0], a1 = zp[1], a2 = zp[2], a3 = zp[3];
  V2x2 v0 = __builtin_bit_cast(V2x2, a0), v1 = __builtin_bit_cast(V2x2, a1);
  V2x2 v2 = __builtin_bit_cast(V2x2, a2), v3 = __builtin_bit_cast(V2x2, a3);
  Zr z;
  z.p0 = v0.lo; z.p1 = v0.hi; z.p2 = v1.lo; z.p3 = v1.hi;
  z.p4 = v2.lo; z.p5 = v2.hi; z.p6 = v3.lo; z.p7 = v3.hi;
  return z;
}

__device__ __forceinline__ Row load_row(const float* p) {
  const float4* cp = (const float4*)p;
  Row rw; rw.c0 = cp[0]; rw.c1 = cp[1]; rw.c2 = cp[2]; rw.c3 = cp[3];
  return rw;
}

__device__ __forceinline__ float l1norm(Zr z) {
  float t0 = fabsf(z.p0.x) + fabsf(z.p0.y), t1 = fabsf(z.p1.x) + fabsf(z.p1.y);
  float t2 = fabsf(z.p2.x) + fabsf(z.p2.y), t3 = fabsf(z.p3.x) + fabsf(z.p3.y);
  float t4 = fabsf(z.p4.x) + fabsf(z.p4.y), t5 = fabsf(z.p5.x) + fabsf(z.p5.y);
  float t6 = fabsf(z.p6.x) + fabsf(z.p6.y), t7 = fabsf(z.p7.x) + fabsf(z.p7.y);
  return ((t0 + t1) + (t2 + t3)) + ((t4 + t5) + (t6 + t7));
}

// fp32 -> bf16 (RNE) and back; fast-path only (window absorbs any mode diff).
__device__ __forceinline__ unsigned int f2bf(float x) {
  unsigned int u = __float_as_uint(x);
  return (u + 0x7FFFu + ((u >> 16) & 1u)) >> 16;
}
__device__ __forceinline__ float bf2f(unsigned int b) {
  return __uint_as_float(b << 16);
}

// stage one residual: fp32 copy + bf16 hi/lo split (identical math to R7)
__device__ __forceinline__ void stage_zr(Zr zr, unsigned int* zqp, float* zbp) {
  v2f* zb2 = (v2f*)zbp;
  zb2[0]=zr.p0; zb2[1]=zr.p1; zb2[2]=zr.p2; zb2[3]=zr.p3;
  zb2[4]=zr.p4; zb2[5]=zr.p5; zb2[6]=zr.p6; zb2[7]=zr.p7;
  v2f P; unsigned h0, h1, l0, l1;
#define PK(I, PP)                                                             \
  P = PP; h0 = f2bf(P.x); h1 = f2bf(P.y); zqp[I] = h0 | (h1 << 16);           \
  l0 = f2bf(__fsub_rn(P.x, bf2f(h0))); l1 = f2bf(__fsub_rn(P.y, bf2f(h1)));   \
  zqp[8 + I] = l0 | (l1 << 16);
  PK(0, zr.p0) PK(1, zr.p1) PK(2, zr.p2) PK(3, zr.p3)
  PK(4, zr.p4) PK(5, zr.p5) PK(6, zr.p6) PK(7, zr.p7)
#undef PK
}

// ---------------------------------------------------------------------------
// Prep: split-negate codebook into ws A-frag region + esq table.
// ---------------------------------------------------------------------------
__global__ void vq_prep(const float* __restrict__ emb,
                        unsigned int* __restrict__ ws) {
  const int row = blockIdx.x * 256 + threadIdx.x;   // 16384 rows (n*1024+k)
  const float* c = emb + row * 16;
  unsigned int o[16];
#pragma unroll
  for (int u = 0; u < 8; ++u) {
    float a = -c[2 * u], b = -c[2 * u + 1];
    unsigned int h0 = f2bf(a), h1 = f2bf(b);
    o[u] = h0 | (h1 << 16);
    unsigned int l0 = f2bf(__fsub_rn(a, bf2f(h0)));
    unsigned int l1 = f2bf(__fsub_rn(b, bf2f(h1)));
    o[8 + u] = l0 | (l1 << 16);
  }
  u32x4* dst = (u32x4*)ws + row * 4;
#pragma unroll
  for (int j = 0; j < 4; ++j)
    dst[j] = (u32x4){o[4 * j], o[4 * j + 1], o[4 * j + 2], o[4 * j + 3]};
  float* esqg = (float*)(ws + 16384 * 16);
  esqg[row] = np_sumsq(load_zr(c));
}

// ---------------------------------------------------------------------------
// Kernel 1: MFMA scan (R9-verified) + per-scan adaptive window + gated
// fallback. wepsb = 1e-6*||zr||_1 + 1.5e-5 soundly bounds 2x(total fast-vs-ref
// discrepancy): bf16-split eps cross terms (2^-17*||zr||_1/16, |c|<1/16),
// MFMA accum rounding, ref-chain rounding, fp32-sqrt tie compression.
// ---------------------------------------------------------------------------
__global__ __launch_bounds__(256, 4) void vq_main(
    const float* __restrict__ z, const float* __restrict__ emb,
    const unsigned int* __restrict__ ws, float* __restrict__ out) {
  __shared__ float esq[KC];                    // 4 KB
  __shared__ float ehs[KC];                    // 4 KB
  __shared__ unsigned int zq[4 * SCW * 16];    // 8 KB bf16-split residuals
  __shared__ float zb[4 * SCW * 16];           // 8 KB fp32 residuals (24 KB)
  const int tid   = threadIdx.x;
  const int bx    = blockIdx.x;
  const int n     = bx & 15;
  const int bbase = (bx >> 4) * 128;
  const int w     = tid >> 6;
  const int lane  = tid & 63;
  const int q     = lane >> 4;
  const int c16   = lane & 15;
  const int sc    = lane & 31;                 // scan within wave (twin lanes)
  const float* embn = emb + n * (KC * ED);
  const u32x4* wsn  = (const u32x4*)ws + n * (KC * 4);
  const float* esqg = (const float*)(ws + 16384 * 16) + n * KC;

  for (int k = tid; k < KC; k += 256) {
    float s = esqg[k];
    esq[k] = s; ehs[k] = 0.5f * s;
  }
  if (bx == 0 && tid == 0) {
    out[0] = 0.f;
    out[OFF_OH + 0] = 0.f; out[OFF_OH + 1] = 0.f; out[OFF_OH + 2] = 0.f;
    out[OFF_OH + OH_ELEMS - 1] = 0.f;
  }
  __syncthreads();

  const int scanB = bbase + w * SCW + sc;
  Zr zr = load_zr(z + scanB * DIMD + n * ED);
  unsigned int* zqw = zq + w * (SCW * 16);
  float*        zbw = zb + w * (SCW * 16);
  if (lane < SCW) stage_zr(zr, zqw + sc * 16, zbw + sc * 16);

  const int gtid = bx * 256 + tid;             // 0 .. NTHR-1
  f32x4* f4 = (f32x4*)(out + OFF_OH + 3);      // 16B-aligned, ext-vector type
  const f32x4 zf4 = {0.f, 0.f, 0.f, 0.f};
  int sIdx = 0, fcnt = 0;
  int bi = 0;

  for (int dep = 0; dep < 3; ++dep) {
    asm volatile("s_waitcnt lgkmcnt(0)" ::: "memory");
    u32x4 B0u = *(const u32x4*)(zqw + ((0 * 16 + c16) * 16 + q * 4));
    u32x4 B1u = *(const u32x4*)(zqw + ((1 * 16 + c16) * 16 + q * 4));
    bshort8 b0 = __builtin_bit_cast(bshort8, B0u);
    bshort8 b1 = __builtin_bit_cast(bshort8, B1u);

    float m1_0 = 3.0e38f, m1_1 = 3.0e38f;
    float m2_0 = 3.0e38f, m2_1 = 3.0e38f;
    int   k1_0 = 0, k1_1 = 0;
    const int qc4 = q * 4;
    const int aoff = c16 * 4 + q, boff = c16 * 4 + ((q + 2) & 3);

    // prefetch ct=0
    u32x4 A1n = wsn[aoff], A2n = wsn[boff];
    float4 ehn = ((const float4*)ehs)[q];

    for (int ct = 0; ct < 64; ++ct) {
      u32x4 A1c = A1n, A2c = A2n;
      f32x4 ehv = __builtin_bit_cast(f32x4, ehn);
      if (ct < 63) {
        const int nb = (ct + 1) * 64;
        A1n = wsn[nb + aoff];
        A2n = wsn[nb + boff];
        ehn = ((const float4*)ehs)[(ct + 1) * 4 + q];
      }
      if (fcnt != 2) {                          // 2 fill stores per 3 cts
        int sl = sIdx * NTHR + gtid; ++sIdx;
        if (sl < F4N) __builtin_nontemporal_store(zf4, f4 + sl);
      }
      fcnt = (fcnt == 2) ? 0 : fcnt + 1;
      bshort8 a1 = __builtin_bit_cast(bshort8, A1c);
      bshort8 a2 = __builtin_bit_cast(bshort8, A2c);
      const int cbase = ct * 16 + qc4;
#define UPD(V, CODE, M1, K1, M2)                                              \
      { float v_ = (V);                                                       \
        M2 = __builtin_amdgcn_fmed3f(v_, M1, M2);                             \
        bool lt_ = v_ < M1; M1 = lt_ ? v_ : M1; K1 = lt_ ? (CODE) : K1; }
#define DOST(BV, M1, K1, M2)                                                  \
      { f32x4 d1 = __builtin_amdgcn_mfma_f32_16x16x32_bf16(a1, BV, ehv, 0,0,0);\
        f32x4 dd = __builtin_amdgcn_mfma_f32_16x16x32_bf16(a2, BV, d1, 0,0,0);\
        UPD(dd.x, cbase + 0, M1, K1, M2)                                      \
        UPD(dd.y, cbase + 1, M1, K1, M2)                                      \
        UPD(dd.z, cbase + 2, M1, K1, M2)                                      \
        UPD(dd.w, cbase + 3, M1, K1, M2) }
      DOST(b0, m1_0, k1_0, m2_0)
      DOST(b1, m1_1, k1_1, m2_1)
#undef DOST
#undef UPD
    }
    // cross-quad reduce: lanes {s, s^16, s^32, s^48} share a scan per tile
#define MERGE3(M1, K1, M2, OFF)                                               \
    { float om = __shfl_xor(M1, OFF); int ok = __shfl_xor(K1, OFF);           \
      float os = __shfl_xor(M2, OFF);                                         \
      float hi = fmaxf(M1, om);                                               \
      M2 = fminf(fminf(M2, os), hi);                                          \
      bool bw = (om < M1) || (om == M1 && ok < K1);                           \
      M1 = bw ? om : M1; K1 = bw ? ok : K1; }
    MERGE3(m1_0, k1_0, m2_0, 16) MERGE3(m1_0, k1_0, m2_0, 32)
    MERGE3(m1_1, k1_1, m2_1, 16) MERGE3(m1_1, k1_1, m2_1, 32)
#undef MERGE3
    // lane (l&31) owns scan l&31; tile = (l&31)>=16
    const bool t1 = (sc >= 16);
    float m1F = t1 ? m1_1 : m1_0;
    float m2F = t1 ? m2_1 : m2_0;
    int   k1F = t1 ? k1_1 : k1_0;

    // per-scan sound ambiguity window
    const float wepsb = fmaf(l1norm(zr), 1.0e-6f, 1.5e-5f);
    bool fb = (lane < SCW) && (__fsub_rn(m2F, m1F) < wepsb);
    unsigned long long mask = __ballot(fb);
    while (mask) {
      int ss = __ffsll((unsigned long long)mask) - 1;
      mask &= (mask - 1);
      Zr zs = load_zr(zbw + ss * 16);          // broadcast read
      float zsq = np_sumsq(zs);
      float gme = __shfl(m1F, ss) + __shfl(wepsb, ss);   // gate threshold
      float db = 3.0e38f; int kb = 0;
      for (int i = 0; i < 16; ++i) {
        int kk = i * 64 + lane;
        Row rw = load_row(embn + kk * 16);
        if (fastv_s(zs, rw, ehs[kk]) < gme) {  // gate: skip fp64 sqrt
          float d = ref_d(zs, rw, zsq, esq[kk]);
          if (d < db) { db = d; kb = kk; }     // strict < => first within lane
        }
      }
#pragma unroll
      for (int off = 1; off < 64; off <<= 1) { // lexicographic (d,k) min
        float od = __shfl_xor(db, off); int ok = __shfl_xor(kb, off);
        if (od < db || (od == db && ok < kb)) { db = od; kb = ok; }
      }
      if (lane == ss) k1F = kb;
    }
    k1F = __shfl(k1F, sc);                     // twin-broadcast (lanes >= 32)
    bi = k1F;
    // residual update (fp32, ref-exact elementwise chain)
    zr = sub_row(zr, load_row(embn + k1F * 16));
    if (dep < 2 && lane < SCW) stage_zr(zr, zqw + sc * 16, zbw + sc * 16);
  }
  for (; sIdx < 128; ++sIdx) {                 // safety flush (normally none)
    int sl = sIdx * NTHR + gtid;
    if (sl < F4N) __builtin_nontemporal_store(zf4, f4 + sl);
  }
  // lanes < 32 write idx + mean(q) = (z_orig - zr_final)/3 (verified path)
  if (lane < SCW) {
    out[OFF_IDX + scanB * NSUB + n] = (float)bi;
    Zr zo = load_zr(z + scanB * DIMD + n * ED);
    float* mp2 = out + OFF_ZQ + scanB * DIMD + n * ED;
    mp2[0]  = __fdiv_rn(__fsub_rn(zo.p0.x, zr.p0.x), 3.0f);
    mp2[1]  = __fdiv_rn(__fsub_rn(zo.p0.y, zr.p0.y), 3.0f);
    mp2[2]  = __fdiv_rn(__fsub_rn(zo.p1.x, zr.p1.x), 3.0f);
    mp2[3]  = __fdiv_rn(__fsub_rn(zo.p1.y, zr.p1.y), 3.0f);
    mp2[4]  = __fdiv_rn(__fsub_rn(zo.p2.x, zr.p2.x), 3.0f);
    mp2[5]  = __fdiv_rn(__fsub_rn(zo.p2.y, zr.p2.y), 3.0f);
    mp2[6]  = __fdiv_rn(__fsub_rn(zo.p3.x, zr.p3.x), 3.0f);
    mp2[7]  = __fdiv_rn(__fsub_rn(zo.p3.y, zr.p3.y), 3.0f);
    mp2[8]  = __fdiv_rn(__fsub_rn(zo.p4.x, zr.p4.x), 3.0f);
    mp2[9]  = __fdiv_rn(__fsub_rn(zo.p4.y, zr.p4.y), 3.0f);
    mp2[10] = __fdiv_rn(__fsub_rn(zo.p5.x, zr.p5.x), 3.0f);
    mp2[11] = __fdiv_rn(__fsub_rn(zo.p5.y, zr.p5.y), 3.0f);
    mp2[12] = __fdiv_rn(__fsub_rn(zo.p6.x, zr.p6.x), 3.0f);
    mp2[13] = __fdiv_rn(__fsub_rn(zo.p6.y, zr.p6.y), 3.0f);
    mp2[14] = __fdiv_rn(__fsub_rn(zo.p7.x, zr.p7.x), 3.0f);
    mp2[15] = __fdiv_rn(__fsub_rn(zo.p7.y, zr.p7.y), 3.0f);
  }
}

// ---------------------------------------------------------------------------
// Kernel 2: scatter the ones into the (already zeroed) onehot region.
// ---------------------------------------------------------------------------
__global__ void vq_ones(float* __restrict__ out) {
  int g = blockIdx.x * 256 + threadIdx.x;          // 0 .. 131071 == b*16+n
  int k = (int)out[OFF_IDX + g];
  out[OFF_OH + g * KC + k] = 1.0f;
}

// ---------------------------------------------------------------------------
// Kernel 3: z_q = mean @ W + b, straight-through output, loss.
// ---------------------------------------------------------------------------
#define TB 16
__global__ __launch_bounds__(256, 2) void vq_head(
    const float* __restrict__ z, const float* __restrict__ W,
    const float* __restrict__ bias, float* __restrict__ out) {
  __shared__ float ml[TB][DIMD];   // 16KB
  __shared__ double reds[4];
  const int t  = threadIdx.x;
  const int r0 = blockIdx.x * TB;
  for (int j = t; j < TB * DIMD; j += 256) {
    int r = j >> 8, d = j & 255;
    ml[r][d] = out[OFF_ZQ + (r0 + r) * DIMD + d];
  }
  __syncthreads();
  float acc[TB];
#pragma unroll
  for (int r = 0; r < TB; ++r) acc[r] = 0.f;
  for (int d = 0; d < DIMD; ++d) {
    float w = W[d * DIMD + t];
#pragma unroll
    for (int r = 0; r < TB; ++r) acc[r] = fmaf(ml[r][d], w, acc[r]);
  }
  const float bv = bias[t];
  double lp = 0.0;
#pragma unroll
  for (int r = 0; r < TB; ++r) {
    float zq   = acc[r] + bv;
    float zv   = z[(r0 + r) * DIMD + t];
    float diff = zq - zv;
    out[OFF_ZQ + (r0 + r) * DIMD + t] = zv + diff;
    lp += (double)diff * (double)diff;
  }
#pragma unroll
  for (int o = 32; o > 0; o >>= 1) lp += __shfl_down(lp, o);
  if ((t & 63) == 0) reds[t >> 6] = lp;
  __syncthreads();
  if (t == 0) {
    double tot = reds[0] + reds[1] + reds[2] + reds[3];
    atomicAdd(out, (float)(tot * (1.25 / (double)(BQ * DIMD))));
  }
}

extern "C" void kernel_launch(void* const* d_in, const int* in_sizes, int n_in,
                              void* d_out, int out_size, void* d_ws, size_t ws_size,
                              hipStream_t stream) {
  const float* z    = (const float*)d_in[0];
  const float* emb  = (const float*)d_in[1];
  const float* W    = (const float*)d_in[2];
  const float* bias = (const float*)d_in[3];
  float* out = (float*)d_out;
  unsigned int* wsp = (unsigned int*)d_ws;       // 1 MB A-frags + 64 KB esq
  vq_prep<<<dim3(64), dim3(256), 0, stream>>>(emb, wsp);
  vq_main<<<dim3((BQ / 128) * NSUB), dim3(256), 0, stream>>>(z, emb, wsp, out);
  vq_ones<<<dim3((BQ * NSUB) / 256), dim3(256), 0, stream>>>(out);
  vq_head<<<dim3(BQ / TB), dim3(256), 0, stream>>>(z, W, bias, out);
}